// Round 4
// baseline (717.181 us; speedup 1.0000x reference)
//
#include <hip/hip_runtime.h>
#include <hip/hip_bf16.h>
#include <stdint.h>

typedef unsigned short u16;
typedef __attribute__((ext_vector_type(8))) short bf16x8;   // 8 bf16 (4 VGPRs), per guide §3
typedef __attribute__((ext_vector_type(4))) float f32x4;
typedef __attribute__((ext_vector_type(4))) unsigned short u16x4;
typedef __attribute__((ext_vector_type(8))) unsigned short u16x8;

#define DEV __device__ __forceinline__

DEV u16 f2bf(float f){ // round-to-nearest-even f32 -> bf16
  unsigned u = __float_as_uint(f);
  return (u16)((u + 0x7FFFu + ((u >> 16) & 1u)) >> 16);
}
DEV float b2f(u16 v){ return __uint_as_float(((unsigned)v) << 16); }

DEV f32x4 MFMA(bf16x8 a, bf16x8 b, f32x4 c){
  // D = A*B + C ; a = rows of A (M,K), b = rows of B^T (N,K) -> computes A·B
  return __builtin_amdgcn_mfma_f32_16x16x32_bf16(a, b, c, 0, 0, 0);
}

// ---------------- elementwise f32 -> bf16 ----------------
__global__ __launch_bounds__(256) void cvt_f32_bf16(const float* __restrict__ in,
                                                    u16* __restrict__ out, int n4){
  int i = blockIdx.x * 256 + threadIdx.x;
  if (i >= n4) return;
  f32x4 v = ((const f32x4*)in)[i];
  u16x4 o;
  o[0] = f2bf(v[0]); o[1] = f2bf(v[1]); o[2] = f2bf(v[2]); o[3] = f2bf(v[3]);
  ((u16x4*)out)[i] = o;
}

// ---------------- transpose + convert: out[c][r] = bf16(in[r][c]) ----------------
__global__ __launch_bounds__(256) void tcvt(const float* __restrict__ in, u16* __restrict__ out,
                                            int R, int C){
  __shared__ float tile[64][65];
  int c0 = blockIdx.x * 64, r0 = blockIdx.y * 64;
  int t = threadIdx.x;
#pragma unroll
  for (int j = 0; j < 16; j++){
    int idx = j * 256 + t;
    int r = idx >> 6, c = idx & 63;
    tile[r][c] = in[(size_t)(r0 + r) * C + c0 + c];
  }
  __syncthreads();
#pragma unroll
  for (int j = 0; j < 16; j++){
    int idx = j * 256 + t;
    int c = idx >> 6, r = idx & 63;
    out[(size_t)(c0 + c) * R + r0 + r] = f2bf(tile[r][c]);
  }
}

// ---------------- GEMM: out(M,N) = A(M,K) * Bt(N,K)^T + bias ----------------
// 128x128 tile, BK=32, 4 waves (2x2), 4x4 16x16 frags per wave (m93-structure).
// LDS row stride 40 elems (80 B): 16 frag-lanes spread over 20 banks -> 2-way (free).
template<int F32OUT>
__global__ __launch_bounds__(256) void gemm_bt(const u16* __restrict__ A, const u16* __restrict__ Bt,
                                               const float* __restrict__ bias, void* __restrict__ outp,
                                               int M, int N, int K){
  __shared__ __align__(16) u16 smA[128 * 40];
  __shared__ __align__(16) u16 smB[128 * 40];
  int t = threadIdx.x;
  int lane = t & 63, w = t >> 6;
  int wr = w >> 1, wc = w & 1;
  int li = lane & 15, g = lane >> 4;
  int m0 = blockIdx.y * 128, n0 = blockIdx.x * 128;

  int srow = t >> 2, sseg = (t & 3) * 8;          // staging: 64 rows x 4 x 16B
  const u16* Ap0 = A  + (size_t)(m0 + srow) * K + sseg;
  const u16* Ap1 = Ap0 + (size_t)64 * K;
  const u16* Bp0 = Bt + (size_t)(n0 + srow) * K + sseg;
  const u16* Bp1 = Bp0 + (size_t)64 * K;

  f32x4 acc[4][4] = {};
  u16x8 a0 = *(const u16x8*)Ap0, a1 = *(const u16x8*)Ap1;
  u16x8 b0 = *(const u16x8*)Bp0, b1 = *(const u16x8*)Bp1;

  for (int kt = 32; kt <= K; kt += 32){
    __syncthreads();
    *(u16x8*)&smA[srow * 40 + sseg]        = a0;
    *(u16x8*)&smA[(64 + srow) * 40 + sseg] = a1;
    *(u16x8*)&smB[srow * 40 + sseg]        = b0;
    *(u16x8*)&smB[(64 + srow) * 40 + sseg] = b1;
    __syncthreads();
    if (kt < K){
      a0 = *(const u16x8*)(Ap0 + kt); a1 = *(const u16x8*)(Ap1 + kt);
      b0 = *(const u16x8*)(Bp0 + kt); b1 = *(const u16x8*)(Bp1 + kt);
    }
    bf16x8 af[4], bfr[4];
#pragma unroll
    for (int mf = 0; mf < 4; mf++)
      af[mf] = *(const bf16x8*)&smA[(wr * 64 + mf * 16 + li) * 40 + g * 8];
#pragma unroll
    for (int nf = 0; nf < 4; nf++)
      bfr[nf] = *(const bf16x8*)&smB[(wc * 64 + nf * 16 + li) * 40 + g * 8];
#pragma unroll
    for (int mf = 0; mf < 4; mf++)
#pragma unroll
      for (int nf = 0; nf < 4; nf++)
        acc[mf][nf] = MFMA(af[mf], bfr[nf], acc[mf][nf]);
  }

#pragma unroll
  for (int mf = 0; mf < 4; mf++){
    int row = m0 + wr * 64 + mf * 16 + g * 4;
#pragma unroll
    for (int nf = 0; nf < 4; nf++){
      int col = n0 + wc * 64 + nf * 16 + li;
      float bs = bias[col];
#pragma unroll
      for (int r = 0; r < 4; r++){
        float v = acc[mf][nf][r] + bs;
        if (F32OUT) ((float*)outp)[(size_t)(row + r) * N + col] = v;
        else        ((u16*)outp)[(size_t)(row + r) * N + col]  = f2bf(v);
      }
    }
  }
}

// ---------------- RMS (q,k) + scatter into attention layouts ----------------
// qkvb: (B*L, 3072) bf16, cols [0,1024)=q [1024,2048)=k [2048,3072)=v
// q -> qdst (B,H,qL,64) at token qoff+l ; k -> kdst (B,H,3584,64) at token kvoff+l
__global__ __launch_bounds__(256) void rms_scatter(const u16* __restrict__ qkvb, int L,
                                                   const float* __restrict__ gq, const float* __restrict__ gk,
                                                   u16* __restrict__ qdst, int qL, int qoff,
                                                   u16* __restrict__ kdst, int kvoff){
  int tok = blockIdx.x;
  int b = tok / L, l = tok - b * L;
  int t = threadIdx.x;
  int c = t * 4;
  int h = t >> 4;
  int d = c & 63;
  const u16* rowq = qkvb + (size_t)tok * 3072 + c;
  u16x4 qv = *(const u16x4*)rowq;
  u16x4 kv = *(const u16x4*)(rowq + 1024);
  float qf[4], kf[4], ssq = 0.f, ssk = 0.f;
#pragma unroll
  for (int j = 0; j < 4; j++){
    qf[j] = b2f(qv[j]); kf[j] = b2f(kv[j]);
    ssq += qf[j] * qf[j]; ssk += kf[j] * kf[j];
  }
#pragma unroll
  for (int msk = 1; msk < 16; msk <<= 1){
    ssq += __shfl_xor(ssq, msk);
    ssk += __shfl_xor(ssk, msk);
  }
  float sq = 8.0f / fmaxf(sqrtf(ssq), 1e-12f);   // SCALE_RMS = sqrt(64) = 8
  float sk = 8.0f / fmaxf(sqrtf(ssk), 1e-12f);
  u16x4 qo, ko;
#pragma unroll
  for (int j = 0; j < 4; j++){
    qo[j] = f2bf(qf[j] * sq * gq[h * 64 + d + j]);
    ko[j] = f2bf(kf[j] * sk * gk[h * 64 + d + j]);
  }
  *(u16x4*)(qdst + ((size_t)(b * 16 + h) * qL + qoff + l) * 64 + d) = qo;
  *(u16x4*)(kdst + ((size_t)(b * 16 + h) * 3584 + kvoff + l) * 64 + d) = ko;
}

// ---------------- V transpose: qkvb v-part -> vT (B,H,64,3584) ----------------
__global__ __launch_bounds__(256) void vtrans(const u16* __restrict__ qkvb, int L,
                                              u16* __restrict__ vT, int kvoff){
  __shared__ u16 tile[64][65];
  int l0 = blockIdx.x * 64; int h = blockIdx.y; int b = blockIdx.z;
  int t = threadIdx.x;
  // 64x64 tile = 4096 elems = 16 passes of 256 threads
#pragma unroll
  for (int j = 0; j < 16; j++){
    int idx = j * 256 + t;
    int r = idx >> 6, d = idx & 63;
    tile[r][d] = qkvb[(size_t)(b * L + l0 + r) * 3072 + 2048 + h * 64 + d];
  }
  __syncthreads();
#pragma unroll
  for (int j = 0; j < 16; j++){
    int idx = j * 256 + t;
    int d = idx >> 6, r = idx & 63;
    vT[((size_t)(b * 16 + h) * 64 + d) * 3584 + kvoff + l0 + r] = tile[r][d];
  }
}

// ---------------- flash attention ----------------
// q: (B,H,Lq,64) ; kmat: (B,H,3584,64) starting at kvoff, Lk keys ; vT: (B,H,64,3584)
// out: (B, L, H*64) bf16 ; queries qi<L0 -> out0, else out1 (token qi-L0)
__global__ __launch_bounds__(256) void attn(const u16* __restrict__ q, int Lq,
                                            const u16* __restrict__ kmat, const u16* __restrict__ vT,
                                            int kvoff, int Lk,
                                            u16* __restrict__ out0, int L0,
                                            u16* __restrict__ out1, int L1){
  __shared__ __align__(16) u16 smK[32 * 72];     // [key][feat], row stride 72 elems
  __shared__ __align__(16) u16 smV[64 * 40];     // [d][kv], row stride 40 elems
  __shared__ __align__(16) u16 smP[4][16 * 40];  // per-wave P [qrow][kv], stride 40
  int qb = blockIdx.x, h = blockIdx.y, b = blockIdx.z;
  int bh = b * 16 + h;
  int t = threadIdx.x, lane = t & 63, w = t >> 6;
  int li = lane & 15, g = lane >> 4;

  const u16* qrow = q + ((size_t)bh * Lq + qb * 64 + w * 16 + li) * 64;
  bf16x8 qf0 = *(const bf16x8*)(qrow + g * 8);
  bf16x8 qf1 = *(const bf16x8*)(qrow + 32 + g * 8);

  f32x4 acc[4] = {};
  float mrun[4], lrun[4];
#pragma unroll
  for (int r = 0; r < 4; r++){ mrun[r] = -1e30f; lrun[r] = 0.f; }

  int skv = t >> 3, sseg = t & 7;   // K staging: 32 rows x 8 x 16B
  int svd = t >> 2, svseg = t & 3;  // V staging: 64 rows x 4 x 16B
  const u16* kbase = kmat + ((size_t)bh * 3584 + kvoff) * 64;
  const u16* vbase = vT + (size_t)bh * 64 * 3584 + kvoff;
  u16* pp = &smP[w][0];

  for (int kt = 0; kt < Lk; kt += 32){
    u16x8 kv8 = *(const u16x8*)(kbase + (size_t)(kt + skv) * 64 + sseg * 8);
    u16x8 vv8 = *(const u16x8*)(vbase + (size_t)svd * 3584 + kt + svseg * 8);
    __syncthreads();   // prior tile fully consumed
    *(u16x8*)&smK[skv * 72 + sseg * 8] = kv8;
    *(u16x8*)&smV[svd * 40 + svseg * 8] = vv8;
    __syncthreads();

    // S = Q K^T (16 q-rows x 32 keys)
    f32x4 s0 = {}, s1 = {};
    {
      bf16x8 k00 = *(const bf16x8*)&smK[li * 72 + g * 8];
      bf16x8 k01 = *(const bf16x8*)&smK[li * 72 + 32 + g * 8];
      bf16x8 k10 = *(const bf16x8*)&smK[(16 + li) * 72 + g * 8];
      bf16x8 k11 = *(const bf16x8*)&smK[(16 + li) * 72 + 32 + g * 8];
      s0 = MFMA(qf0, k00, s0); s0 = MFMA(qf1, k01, s0);
      s1 = MFMA(qf0, k10, s1); s1 = MFMA(qf1, k11, s1);
    }

    float p0[4], p1[4], al[4];
#pragma unroll
    for (int r = 0; r < 4; r++){
      float sa = s0[r] * 0.125f, sb = s1[r] * 0.125f;  // SCALE_ATTN
      float rm = fmaxf(sa, sb);
#pragma unroll
      for (int msk = 1; msk < 16; msk <<= 1) rm = fmaxf(rm, __shfl_xor(rm, msk));
      float mn = fmaxf(mrun[r], rm);
      al[r] = __expf(mrun[r] - mn);
      mrun[r] = mn;
      p0[r] = __expf(sa - mn);
      p1[r] = __expf(sb - mn);
      float ps = p0[r] + p1[r];
#pragma unroll
      for (int msk = 1; msk < 16; msk <<= 1) ps += __shfl_xor(ps, msk);
      lrun[r] = lrun[r] * al[r] + ps;
    }
#pragma unroll
    for (int dt = 0; dt < 4; dt++)
#pragma unroll
      for (int r = 0; r < 4; r++) acc[dt][r] *= al[r];

    // P -> LDS (transpose to A-fragment layout), then PV
#pragma unroll
    for (int r = 0; r < 4; r++){
      pp[(g * 4 + r) * 40 + li]      = f2bf(p0[r]);
      pp[(g * 4 + r) * 40 + 16 + li] = f2bf(p1[r]);
    }
    bf16x8 pf = *(const bf16x8*)&pp[li * 40 + g * 8];
#pragma unroll
    for (int dt = 0; dt < 4; dt++){
      bf16x8 vf = *(const bf16x8*)&smV[(dt * 16 + li) * 40 + g * 8];
      acc[dt] = MFMA(pf, vf, acc[dt]);
    }
  }

  // epilogue: divide by l, scatter to (B,L,C)
#pragma unroll
  for (int r = 0; r < 4; r++){
    int qi = qb * 64 + w * 16 + g * 4 + r;
    float inv = 1.0f / lrun[r];
    u16* dst; size_t basei;
    if (qi < L0){ dst = out0; basei = ((size_t)(b * L0 + qi)) * 1024 + h * 64; }
    else        { dst = out1; basei = ((size_t)(b * L1 + (qi - L0))) * 1024 + h * 64; }
#pragma unroll
    for (int dt = 0; dt < 4; dt++)
      dst[basei + dt * 16 + li] = f2bf(acc[dt][r] * inv);
  }
}

// ---------------- launch ----------------
extern "C" void kernel_launch(void* const* d_in, const int* in_sizes, int n_in,
                              void* d_out, int out_size, void* d_ws, size_t ws_size,
                              hipStream_t stream){
  (void)in_sizes; (void)n_in; (void)out_size; (void)ws_size;
  const float* x[3]    = {(const float*)d_in[0],  (const float*)d_in[7],  (const float*)d_in[14]};
  const float* Wqkv[3] = {(const float*)d_in[1],  (const float*)d_in[8],  (const float*)d_in[15]};
  const float* bqkv[3] = {(const float*)d_in[2],  (const float*)d_in[9],  (const float*)d_in[16]};
  const float* gq[3]   = {(const float*)d_in[3],  (const float*)d_in[10], (const float*)d_in[17]};
  const float* gk[3]   = {(const float*)d_in[4],  (const float*)d_in[11], (const float*)d_in[18]};
  const float* Wout[3] = {(const float*)d_in[5],  (const float*)d_in[12], (const float*)d_in[19]};
  const float* bout[3] = {(const float*)d_in[6],  (const float*)d_in[13], (const float*)d_in[20]};
  float* outp = (float*)d_out;

  const int Ms[3] = {4096, 2048, 1024};   // B*L per modality
  const int Ls[3] = {2048, 1024, 512};
  const int kvoffs[3] = {1536, 0, 1024};  // joint KV order: [texture, color, shape]

  u16* base = (u16*)d_ws;
  size_t off = 0;
  auto nxt = [&](size_t e){ u16* r = base + off; off += e; return r; };
  u16* xbf[3];  for (int m = 0; m < 3; m++) xbf[m]  = nxt((size_t)Ms[m] * 1024);
  u16* WqT[3];  for (int m = 0; m < 3; m++) WqT[m]  = nxt((size_t)3072 * 1024);
  u16* WoT[3];  for (int m = 0; m < 3; m++) WoT[m]  = nxt((size_t)1024 * 1024);
  u16* qkvb[3]; for (int m = 0; m < 3; m++) qkvb[m] = nxt((size_t)Ms[m] * 3072);
  u16* qA = nxt((size_t)2 * 16 * 2048 * 64);
  u16* qB = nxt((size_t)2 * 16 * 1536 * 64);
  u16* kB = nxt((size_t)2 * 16 * 3584 * 64);
  // aliases (disjoint lifetimes, stream-ordered):
  u16* vT = WqT[0];                        // vT (7.34M elems) reuses WqT block (9.44M): WqT dead after QKV GEMMs
  u16* hb[3]; for (int m = 0; m < 3; m++) hb[m] = xbf[m];  // same sizes; xbf dead after QKV GEMMs

  // 1) conversions
  for (int m = 0; m < 3; m++){
    int n4 = Ms[m] * 1024 / 4;
    cvt_f32_bf16<<<n4 / 256, 256, 0, stream>>>(x[m], xbf[m], n4);
    tcvt<<<dim3(3072 / 64, 1024 / 64), 256, 0, stream>>>(Wqkv[m], WqT[m], 1024, 3072);
    tcvt<<<dim3(1024 / 64, 1024 / 64), 256, 0, stream>>>(Wout[m], WoT[m], 1024, 1024);
  }
  // 2) qkv projections
  for (int m = 0; m < 3; m++)
    gemm_bt<0><<<dim3(3072 / 128, Ms[m] / 128), 256, 0, stream>>>(
        xbf[m], WqT[m], bqkv[m], qkvb[m], Ms[m], 3072, 1024);
  // 3) RMS + scatter q/k ; transpose v
  rms_scatter<<<Ms[0], 256, 0, stream>>>(qkvb[0], Ls[0], gq[0], gk[0], qA, 2048, 0,    kB, 1536);
  rms_scatter<<<Ms[1], 256, 0, stream>>>(qkvb[1], Ls[1], gq[1], gk[1], qB, 1536, 0,    kB, 0);
  rms_scatter<<<Ms[2], 256, 0, stream>>>(qkvb[2], Ls[2], gq[2], gk[2], qB, 1536, 1024, kB, 1024);
  for (int m = 0; m < 3; m++)
    vtrans<<<dim3(Ls[m] / 64, 16, 2), 256, 0, stream>>>(qkvb[m], Ls[m], vT, kvoffs[m]);
  // 4) attentions
  attn<<<dim3(2048 / 64, 16, 2), 256, 0, stream>>>(qA, 2048, kB, vT, 1536, 2048,
                                                   hb[0], 2048, hb[0], 2048);
  attn<<<dim3(1536 / 64, 16, 2), 256, 0, stream>>>(qB, 1536, kB, vT, 0, 3584,
                                                   hb[1], 1024, hb[2], 512);
  // 5) output projections
  float* outs[3] = {outp, outp + (size_t)4096 * 1024, outp + (size_t)6144 * 1024};
  for (int m = 0; m < 3; m++)
    gemm_bt<1><<<dim3(1024 / 128, Ms[m] / 128), 256, 0, stream>>>(
        hb[m], WoT[m], bout[m], outs[m], Ms[m], 1024, 1024);
}

// Round 5
// 668.605 us; speedup vs baseline: 1.0727x; 1.0727x over previous
//
#include <hip/hip_runtime.h>
#include <hip/hip_bf16.h>
#include <stdint.h>

typedef unsigned short u16;
typedef __attribute__((ext_vector_type(8))) short bf16x8;   // 8 bf16 (4 VGPRs), per guide §3
typedef __attribute__((ext_vector_type(4))) float f32x4;
typedef __attribute__((ext_vector_type(4))) unsigned short u16x4;
typedef __attribute__((ext_vector_type(8))) unsigned short u16x8;

#define DEV __device__ __forceinline__

DEV u16 f2bf(float f){ // round-to-nearest-even f32 -> bf16
  unsigned u = __float_as_uint(f);
  return (u16)((u + 0x7FFFu + ((u >> 16) & 1u)) >> 16);
}
DEV float b2f(u16 v){ return __uint_as_float(((unsigned)v) << 16); }

DEV f32x4 MFMA(bf16x8 a, bf16x8 b, f32x4 c){
  // D = A*B + C ; a = rows of A (M,K), b = rows of B^T (N,K) -> computes A·B
  return __builtin_amdgcn_mfma_f32_16x16x32_bf16(a, b, c, 0, 0, 0);
}

// ---------------- elementwise f32 -> bf16 ----------------
__global__ __launch_bounds__(256) void cvt_f32_bf16(const float* __restrict__ in,
                                                    u16* __restrict__ out, int n4){
  int i = blockIdx.x * 256 + threadIdx.x;
  if (i >= n4) return;
  f32x4 v = ((const f32x4*)in)[i];
  u16x4 o;
  o[0] = f2bf(v[0]); o[1] = f2bf(v[1]); o[2] = f2bf(v[2]); o[3] = f2bf(v[3]);
  ((u16x4*)out)[i] = o;
}

// ---------------- transpose + convert: out[c][r] = bf16(in[r][c]) ----------------
__global__ __launch_bounds__(256) void tcvt(const float* __restrict__ in, u16* __restrict__ out,
                                            int R, int C){
  __shared__ float tile[64][65];
  int c0 = blockIdx.x * 64, r0 = blockIdx.y * 64;
  int t = threadIdx.x;
#pragma unroll
  for (int j = 0; j < 16; j++){
    int idx = j * 256 + t;
    int r = idx >> 6, c = idx & 63;
    tile[r][c] = in[(size_t)(r0 + r) * C + c0 + c];
  }
  __syncthreads();
#pragma unroll
  for (int j = 0; j < 16; j++){
    int idx = j * 256 + t;
    int c = idx >> 6, r = idx & 63;
    out[(size_t)(c0 + c) * R + r0 + r] = f2bf(tile[r][c]);
  }
}

// ---------------- GEMM: out(M,N) = A(M,K) * Bt(N,K)^T + bias ----------------
// 128x128 tile, BK=32, 4 waves (2x2), 4x4 16x16 frags per wave (m93-structure).
template<int F32OUT>
__global__ __launch_bounds__(256) void gemm_bt(const u16* __restrict__ A, const u16* __restrict__ Bt,
                                               const float* __restrict__ bias, void* __restrict__ outp,
                                               int M, int N, int K){
  __shared__ __align__(16) u16 smA[128 * 40];
  __shared__ __align__(16) u16 smB[128 * 40];
  int t = threadIdx.x;
  int lane = t & 63, w = t >> 6;
  int wr = w >> 1, wc = w & 1;
  int li = lane & 15, g = lane >> 4;
  int m0 = blockIdx.y * 128, n0 = blockIdx.x * 128;

  int srow = t >> 2, sseg = (t & 3) * 8;          // staging: 64 rows x 4 x 16B
  const u16* Ap0 = A  + (size_t)(m0 + srow) * K + sseg;
  const u16* Ap1 = Ap0 + (size_t)64 * K;
  const u16* Bp0 = Bt + (size_t)(n0 + srow) * K + sseg;
  const u16* Bp1 = Bp0 + (size_t)64 * K;

  f32x4 acc[4][4] = {};
  u16x8 a0 = *(const u16x8*)Ap0, a1 = *(const u16x8*)Ap1;
  u16x8 b0 = *(const u16x8*)Bp0, b1 = *(const u16x8*)Bp1;

  for (int kt = 32; kt <= K; kt += 32){
    __syncthreads();
    *(u16x8*)&smA[srow * 40 + sseg]        = a0;
    *(u16x8*)&smA[(64 + srow) * 40 + sseg] = a1;
    *(u16x8*)&smB[srow * 40 + sseg]        = b0;
    *(u16x8*)&smB[(64 + srow) * 40 + sseg] = b1;
    __syncthreads();
    if (kt < K){
      a0 = *(const u16x8*)(Ap0 + kt); a1 = *(const u16x8*)(Ap1 + kt);
      b0 = *(const u16x8*)(Bp0 + kt); b1 = *(const u16x8*)(Bp1 + kt);
    }
    bf16x8 af[4], bfr[4];
#pragma unroll
    for (int mf = 0; mf < 4; mf++)
      af[mf] = *(const bf16x8*)&smA[(wr * 64 + mf * 16 + li) * 40 + g * 8];
#pragma unroll
    for (int nf = 0; nf < 4; nf++)
      bfr[nf] = *(const bf16x8*)&smB[(wc * 64 + nf * 16 + li) * 40 + g * 8];
#pragma unroll
    for (int mf = 0; mf < 4; mf++)
#pragma unroll
      for (int nf = 0; nf < 4; nf++)
        acc[mf][nf] = MFMA(af[mf], bfr[nf], acc[mf][nf]);
  }

#pragma unroll
  for (int mf = 0; mf < 4; mf++){
    int row = m0 + wr * 64 + mf * 16 + g * 4;
#pragma unroll
    for (int nf = 0; nf < 4; nf++){
      int col = n0 + wc * 64 + nf * 16 + li;
      float bs = bias[col];
#pragma unroll
      for (int r = 0; r < 4; r++){
        float v = acc[mf][nf][r] + bs;
        if (F32OUT) ((float*)outp)[(size_t)(row + r) * N + col] = v;
        else        ((u16*)outp)[(size_t)(row + r) * N + col]  = f2bf(v);
      }
    }
  }
}

// ---------------- RMS (q,k) + scatter into attention layouts ----------------
__global__ __launch_bounds__(256) void rms_scatter(const u16* __restrict__ qkvb, int L,
                                                   const float* __restrict__ gq, const float* __restrict__ gk,
                                                   u16* __restrict__ qdst, int qL, int qoff,
                                                   u16* __restrict__ kdst, int kvoff){
  int tok = blockIdx.x;
  int b = tok / L, l = tok - b * L;
  int t = threadIdx.x;
  int c = t * 4;
  int h = t >> 4;
  int d = c & 63;
  const u16* rowq = qkvb + (size_t)tok * 3072 + c;
  u16x4 qv = *(const u16x4*)rowq;
  u16x4 kv = *(const u16x4*)(rowq + 1024);
  float qf[4], kf[4], ssq = 0.f, ssk = 0.f;
#pragma unroll
  for (int j = 0; j < 4; j++){
    qf[j] = b2f(qv[j]); kf[j] = b2f(kv[j]);
    ssq += qf[j] * qf[j]; ssk += kf[j] * kf[j];
  }
#pragma unroll
  for (int msk = 1; msk < 16; msk <<= 1){
    ssq += __shfl_xor(ssq, msk);
    ssk += __shfl_xor(ssk, msk);
  }
  float sq = 8.0f / fmaxf(sqrtf(ssq), 1e-12f);   // SCALE_RMS = sqrt(64) = 8
  float sk = 8.0f / fmaxf(sqrtf(ssk), 1e-12f);
  u16x4 qo, ko;
#pragma unroll
  for (int j = 0; j < 4; j++){
    qo[j] = f2bf(qf[j] * sq * gq[h * 64 + d + j]);
    ko[j] = f2bf(kf[j] * sk * gk[h * 64 + d + j]);
  }
  *(u16x4*)(qdst + ((size_t)(b * 16 + h) * qL + qoff + l) * 64 + d) = qo;
  *(u16x4*)(kdst + ((size_t)(b * 16 + h) * 3584 + kvoff + l) * 64 + d) = ko;
}

// ---------------- V transpose: qkvb v-part -> vT (B,H,64,3584) ----------------
__global__ __launch_bounds__(256) void vtrans(const u16* __restrict__ qkvb, int L,
                                              u16* __restrict__ vT, int kvoff){
  __shared__ u16 tile[64][65];
  int l0 = blockIdx.x * 64; int h = blockIdx.y; int b = blockIdx.z;
  int t = threadIdx.x;
#pragma unroll
  for (int j = 0; j < 16; j++){
    int idx = j * 256 + t;
    int r = idx >> 6, d = idx & 63;
    tile[r][d] = qkvb[(size_t)(b * L + l0 + r) * 3072 + 2048 + h * 64 + d];
  }
  __syncthreads();
#pragma unroll
  for (int j = 0; j < 16; j++){
    int idx = j * 256 + t;
    int d = idx >> 6, r = idx & 63;
    vT[((size_t)(b * 16 + h) * 64 + d) * 3584 + kvoff + l0 + r] = tile[r][d];
  }
}

// ---------------- flash attention (v2) ----------------
// 4 waves x 32 q-rows = 128 q-rows/block; KV tile = 64 keys; exp2-domain softmax;
// lane-local partial row-sums (single reduce in epilogue); reg-prefetch of next K/V tile.
// grid: 1-D, linear = hb + 32*qb so all qb sharing (b,h) K/V land on one XCD (lin%8 const).
__global__ __launch_bounds__(256) void attn(const u16* __restrict__ q, int Lq,
                                            const u16* __restrict__ kmat, const u16* __restrict__ vT,
                                            int kvoff, int Lk,
                                            u16* __restrict__ out0, int L0,
                                            u16* __restrict__ out1, int L1){
  __shared__ __align__(16) u16 smK[64 * 72];      // [key][feat]
  __shared__ __align__(16) u16 smV[64 * 72];      // [d][kv]
  __shared__ __align__(16) u16 smP[4][32 * 68];   // per-wave P [qrow][key]
  int lin = blockIdx.x;
  int qb = lin >> 5, hb = lin & 31;
  int h = hb & 15, b = hb >> 4;
  int bh = b * 16 + h;
  int t = threadIdx.x, lane = t & 63, w = t >> 6;
  int li = lane & 15, g = lane >> 4;

  // Q fragments: rows qb*128 + w*32 + rb*16 + li
  const u16* qbase = q + ((size_t)bh * Lq + qb * 128 + w * 32) * 64;
  bf16x8 qa[2][2];
#pragma unroll
  for (int rb = 0; rb < 2; rb++)
#pragma unroll
    for (int kh = 0; kh < 2; kh++)
      qa[rb][kh] = *(const bf16x8*)(qbase + (size_t)(rb * 16 + li) * 64 + kh * 32 + g * 8);

  f32x4 acc[2][4] = {};
  float mrun[2][4], lsum[2][4];
#pragma unroll
  for (int rb = 0; rb < 2; rb++)
#pragma unroll
    for (int r = 0; r < 4; r++){ mrun[rb][r] = -3.0e38f; lsum[rb][r] = 0.f; }

  const u16* kbase = kmat + ((size_t)bh * 3584 + kvoff) * 64;
  const u16* vbase = vT + (size_t)bh * 64 * 3584 + kvoff;
  int sr = t >> 3, ss = (t & 7) * 8;   // staging: rows sr, sr+32 ; 16B seg ss
  u16* pp = &smP[w][0];

  const float SC = 0.125f * 1.44269504088896340736f;  // SCALE_ATTN * log2(e)

  // prefetch tile 0
  u16x8 ka0 = *(const u16x8*)(kbase + (size_t)sr * 64 + ss);
  u16x8 ka1 = *(const u16x8*)(kbase + (size_t)(sr + 32) * 64 + ss);
  u16x8 va0 = *(const u16x8*)(vbase + (size_t)sr * 3584 + ss);
  u16x8 va1 = *(const u16x8*)(vbase + (size_t)(sr + 32) * 3584 + ss);

  for (int kt = 0; kt < Lk; kt += 64){
    __syncthreads();   // prior tile fully consumed by all waves
    *(u16x8*)&smK[sr * 72 + ss]        = ka0;
    *(u16x8*)&smK[(sr + 32) * 72 + ss] = ka1;
    *(u16x8*)&smV[sr * 72 + ss]        = va0;
    *(u16x8*)&smV[(sr + 32) * 72 + ss] = va1;
    __syncthreads();
    if (kt + 64 < Lk){   // prefetch next tile (hides latency under compute below)
      ka0 = *(const u16x8*)(kbase + (size_t)(kt + 64 + sr) * 64 + ss);
      ka1 = *(const u16x8*)(kbase + (size_t)(kt + 96 + sr) * 64 + ss);
      va0 = *(const u16x8*)(vbase + (size_t)sr * 3584 + kt + 64 + ss);
      va1 = *(const u16x8*)(vbase + (size_t)(sr + 32) * 3584 + kt + 64 + ss);
    }

    // ---- S = Q K^T : 32 q-rows x 64 keys ----
    f32x4 s[2][4] = {};
#pragma unroll
    for (int kf = 0; kf < 4; kf++){
      bf16x8 k0 = *(const bf16x8*)&smK[(kf * 16 + li) * 72 + g * 8];
      bf16x8 k1 = *(const bf16x8*)&smK[(kf * 16 + li) * 72 + 32 + g * 8];
      s[0][kf] = MFMA(qa[0][0], k0, s[0][kf]);
      s[0][kf] = MFMA(qa[0][1], k1, s[0][kf]);
      s[1][kf] = MFMA(qa[1][0], k0, s[1][kf]);
      s[1][kf] = MFMA(qa[1][1], k1, s[1][kf]);
    }

    // ---- online softmax (exp2 domain), lane-local partial sums ----
#pragma unroll
    for (int rb = 0; rb < 2; rb++)
#pragma unroll
    for (int r = 0; r < 4; r++){
      float s0 = s[rb][0][r] * SC, s1 = s[rb][1][r] * SC;
      float s2 = s[rb][2][r] * SC, s3 = s[rb][3][r] * SC;
      float rm = fmaxf(fmaxf(s0, s1), fmaxf(s2, s3));
#pragma unroll
      for (int msk = 1; msk < 16; msk <<= 1) rm = fmaxf(rm, __shfl_xor(rm, msk));
      float mo = mrun[rb][r];
      float mn = fmaxf(mo, rm);
      float al = __builtin_exp2f(mo - mn);
      mrun[rb][r] = mn;
      float p0 = __builtin_exp2f(s0 - mn), p1 = __builtin_exp2f(s1 - mn);
      float p2 = __builtin_exp2f(s2 - mn), p3 = __builtin_exp2f(s3 - mn);
      lsum[rb][r] = lsum[rb][r] * al + (p0 + p1) + (p2 + p3);
#pragma unroll
      for (int dt = 0; dt < 4; dt++) acc[rb][dt][r] *= al;
      int row = rb * 16 + g * 4 + r;
      pp[row * 68 + li]      = f2bf(p0);
      pp[row * 68 + 16 + li] = f2bf(p1);
      pp[row * 68 + 32 + li] = f2bf(p2);
      pp[row * 68 + 48 + li] = f2bf(p3);
    }

    // ---- O += P V ----
    bf16x8 vf[4][2];
#pragma unroll
    for (int dt = 0; dt < 4; dt++){
      vf[dt][0] = *(const bf16x8*)&smV[(dt * 16 + li) * 72 + g * 8];
      vf[dt][1] = *(const bf16x8*)&smV[(dt * 16 + li) * 72 + 32 + g * 8];
    }
#pragma unroll
    for (int rb = 0; rb < 2; rb++){
      bf16x8 pf0 = *(const bf16x8*)&pp[(rb * 16 + li) * 68 + g * 8];
      bf16x8 pf1 = *(const bf16x8*)&pp[(rb * 16 + li) * 68 + 32 + g * 8];
#pragma unroll
      for (int dt = 0; dt < 4; dt++){
        acc[rb][dt] = MFMA(pf0, vf[dt][0], acc[rb][dt]);
        acc[rb][dt] = MFMA(pf1, vf[dt][1], acc[rb][dt]);
      }
    }
  }

  // ---- epilogue: reduce partial sums, normalize, scatter ----
#pragma unroll
  for (int rb = 0; rb < 2; rb++)
#pragma unroll
  for (int r = 0; r < 4; r++){
    float ls = lsum[rb][r];
#pragma unroll
    for (int msk = 1; msk < 16; msk <<= 1) ls += __shfl_xor(ls, msk);
    float inv = 1.0f / ls;
    int qi = qb * 128 + w * 32 + rb * 16 + g * 4 + r;
    u16* dst; size_t basei;
    if (qi < L0){ dst = out0; basei = ((size_t)(b * L0 + qi)) * 1024 + h * 64; }
    else        { dst = out1; basei = ((size_t)(b * L1 + (qi - L0))) * 1024 + h * 64; }
#pragma unroll
    for (int dt = 0; dt < 4; dt++)
      dst[basei + dt * 16 + li] = f2bf(acc[rb][dt][r] * inv);
  }
}

// ---------------- launch ----------------
extern "C" void kernel_launch(void* const* d_in, const int* in_sizes, int n_in,
                              void* d_out, int out_size, void* d_ws, size_t ws_size,
                              hipStream_t stream){
  (void)in_sizes; (void)n_in; (void)out_size; (void)ws_size;
  const float* x[3]    = {(const float*)d_in[0],  (const float*)d_in[7],  (const float*)d_in[14]};
  const float* Wqkv[3] = {(const float*)d_in[1],  (const float*)d_in[8],  (const float*)d_in[15]};
  const float* bqkv[3] = {(const float*)d_in[2],  (const float*)d_in[9],  (const float*)d_in[16]};
  const float* gq[3]   = {(const float*)d_in[3],  (const float*)d_in[10], (const float*)d_in[17]};
  const float* gk[3]   = {(const float*)d_in[4],  (const float*)d_in[11], (const float*)d_in[18]};
  const float* Wout[3] = {(const float*)d_in[5],  (const float*)d_in[12], (const float*)d_in[19]};
  const float* bout[3] = {(const float*)d_in[6],  (const float*)d_in[13], (const float*)d_in[20]};
  float* outp = (float*)d_out;

  const int Ms[3] = {4096, 2048, 1024};   // B*L per modality
  const int Ls[3] = {2048, 1024, 512};
  const int kvoffs[3] = {1536, 0, 1024};  // joint KV order: [texture, color, shape]

  u16* base = (u16*)d_ws;
  size_t off = 0;
  auto nxt = [&](size_t e){ u16* r = base + off; off += e; return r; };
  u16* xbf[3];  for (int m = 0; m < 3; m++) xbf[m]  = nxt((size_t)Ms[m] * 1024);
  u16* WqT[3];  for (int m = 0; m < 3; m++) WqT[m]  = nxt((size_t)3072 * 1024);
  u16* WoT[3];  for (int m = 0; m < 3; m++) WoT[m]  = nxt((size_t)1024 * 1024);
  u16* qkvb[3]; for (int m = 0; m < 3; m++) qkvb[m] = nxt((size_t)Ms[m] * 3072);
  u16* qA = nxt((size_t)2 * 16 * 2048 * 64);
  u16* qB = nxt((size_t)2 * 16 * 1536 * 64);
  u16* kB = nxt((size_t)2 * 16 * 3584 * 64);
  // aliases (disjoint lifetimes, stream-ordered):
  u16* vT = WqT[0];                        // vT reuses WqT block: WqT dead after QKV GEMMs
  u16* hb[3]; for (int m = 0; m < 3; m++) hb[m] = xbf[m];  // xbf dead after QKV GEMMs

  // 1) conversions
  for (int m = 0; m < 3; m++){
    int n4 = Ms[m] * 1024 / 4;
    cvt_f32_bf16<<<n4 / 256, 256, 0, stream>>>(x[m], xbf[m], n4);
    tcvt<<<dim3(3072 / 64, 1024 / 64), 256, 0, stream>>>(Wqkv[m], WqT[m], 1024, 3072);
    tcvt<<<dim3(1024 / 64, 1024 / 64), 256, 0, stream>>>(Wout[m], WoT[m], 1024, 1024);
  }
  // 2) qkv projections
  for (int m = 0; m < 3; m++)
    gemm_bt<0><<<dim3(3072 / 128, Ms[m] / 128), 256, 0, stream>>>(
        xbf[m], WqT[m], bqkv[m], qkvb[m], Ms[m], 3072, 1024);
  // 3) RMS + scatter q/k ; transpose v
  rms_scatter<<<Ms[0], 256, 0, stream>>>(qkvb[0], Ls[0], gq[0], gk[0], qA, 2048, 0,    kB, 1536);
  rms_scatter<<<Ms[1], 256, 0, stream>>>(qkvb[1], Ls[1], gq[1], gk[1], qB, 1536, 0,    kB, 0);
  rms_scatter<<<Ms[2], 256, 0, stream>>>(qkvb[2], Ls[2], gq[2], gk[2], qB, 1536, 1024, kB, 1024);
  for (int m = 0; m < 3; m++)
    vtrans<<<dim3(Ls[m] / 64, 16, 2), 256, 0, stream>>>(qkvb[m], Ls[m], vT, kvoffs[m]);
  // 4) attentions (1-D grid: lin = hb + 32*qb)
  attn<<<(2048 / 128) * 32, 256, 0, stream>>>(qA, 2048, kB, vT, 1536, 2048,
                                              hb[0], 2048, hb[0], 2048);
  attn<<<(1536 / 128) * 32, 256, 0, stream>>>(qB, 1536, kB, vT, 0, 3584,
                                              hb[1], 1024, hb[2], 512);
  // 5) output projections
  float* outs[3] = {outp, outp + (size_t)4096 * 1024, outp + (size_t)6144 * 1024};
  for (int m = 0; m < 3; m++)
    gemm_bt<1><<<dim3(1024 / 128, Ms[m] / 128), 256, 0, stream>>>(
        hb[m], WoT[m], bout[m], outs[m], Ms[m], 1024, 1024);
}

// Round 6
// 665.589 us; speedup vs baseline: 1.0775x; 1.0045x over previous
//
#include <hip/hip_runtime.h>
#include <hip/hip_bf16.h>
#include <stdint.h>

typedef unsigned short u16;
typedef __attribute__((ext_vector_type(8))) short bf16x8;   // 8 bf16 (4 VGPRs), per guide §3
typedef __attribute__((ext_vector_type(4))) float f32x4;
typedef __attribute__((ext_vector_type(4))) unsigned short u16x4;
typedef __attribute__((ext_vector_type(8))) unsigned short u16x8;

#define DEV __device__ __forceinline__

DEV u16 f2bf(float f){ // round-to-nearest-even f32 -> bf16
  unsigned u = __float_as_uint(f);
  return (u16)((u + 0x7FFFu + ((u >> 16) & 1u)) >> 16);
}
DEV float b2f(u16 v){ return __uint_as_float(((unsigned)v) << 16); }

DEV f32x4 MFMA(bf16x8 a, bf16x8 b, f32x4 c){
  // D = A*B + C ; a = rows of A (M,K), b = rows of B^T (N,K) -> computes A·B
  return __builtin_amdgcn_mfma_f32_16x16x32_bf16(a, b, c, 0, 0, 0);
}

// ---------------- elementwise f32 -> bf16 ----------------
__global__ __launch_bounds__(256) void cvt_f32_bf16(const float* __restrict__ in,
                                                    u16* __restrict__ out, int n4){
  int i = blockIdx.x * 256 + threadIdx.x;
  if (i >= n4) return;
  f32x4 v = ((const f32x4*)in)[i];
  u16x4 o;
  o[0] = f2bf(v[0]); o[1] = f2bf(v[1]); o[2] = f2bf(v[2]); o[3] = f2bf(v[3]);
  ((u16x4*)out)[i] = o;
}

// ---------------- transpose + convert: out[c][r] = bf16(in[r][c]) ----------------
__global__ __launch_bounds__(256) void tcvt(const float* __restrict__ in, u16* __restrict__ out,
                                            int R, int C){
  __shared__ float tile[64][65];
  int c0 = blockIdx.x * 64, r0 = blockIdx.y * 64;
  int t = threadIdx.x;
#pragma unroll
  for (int j = 0; j < 16; j++){
    int idx = j * 256 + t;
    int r = idx >> 6, c = idx & 63;
    tile[r][c] = in[(size_t)(r0 + r) * C + c0 + c];
  }
  __syncthreads();
#pragma unroll
  for (int j = 0; j < 16; j++){
    int idx = j * 256 + t;
    int c = idx >> 6, r = idx & 63;
    out[(size_t)(c0 + c) * R + r0 + r] = f2bf(tile[r][c]);
  }
}

// ---------------- GEMM: out(M,N) = A(M,K) * Bt(N,K)^T + bias ----------------
// 128x128 tile, BK=32, 4 waves (2x2), 4x4 16x16 frags per wave (m93-structure).
template<int F32OUT>
__global__ __launch_bounds__(256) void gemm_bt(const u16* __restrict__ A, const u16* __restrict__ Bt,
                                               const float* __restrict__ bias, void* __restrict__ outp,
                                               int M, int N, int K){
  __shared__ __align__(16) u16 smA[128 * 40];
  __shared__ __align__(16) u16 smB[128 * 40];
  int t = threadIdx.x;
  int lane = t & 63, w = t >> 6;
  int wr = w >> 1, wc = w & 1;
  int li = lane & 15, g = lane >> 4;
  int m0 = blockIdx.y * 128, n0 = blockIdx.x * 128;

  int srow = t >> 2, sseg = (t & 3) * 8;          // staging: 64 rows x 4 x 16B
  const u16* Ap0 = A  + (size_t)(m0 + srow) * K + sseg;
  const u16* Ap1 = Ap0 + (size_t)64 * K;
  const u16* Bp0 = Bt + (size_t)(n0 + srow) * K + sseg;
  const u16* Bp1 = Bp0 + (size_t)64 * K;

  f32x4 acc[4][4] = {};
  u16x8 a0 = *(const u16x8*)Ap0, a1 = *(const u16x8*)Ap1;
  u16x8 b0 = *(const u16x8*)Bp0, b1 = *(const u16x8*)Bp1;

  for (int kt = 32; kt <= K; kt += 32){
    __syncthreads();
    *(u16x8*)&smA[srow * 40 + sseg]        = a0;
    *(u16x8*)&smA[(64 + srow) * 40 + sseg] = a1;
    *(u16x8*)&smB[srow * 40 + sseg]        = b0;
    *(u16x8*)&smB[(64 + srow) * 40 + sseg] = b1;
    __syncthreads();
    if (kt < K){
      a0 = *(const u16x8*)(Ap0 + kt); a1 = *(const u16x8*)(Ap1 + kt);
      b0 = *(const u16x8*)(Bp0 + kt); b1 = *(const u16x8*)(Bp1 + kt);
    }
    bf16x8 af[4], bfr[4];
#pragma unroll
    for (int mf = 0; mf < 4; mf++)
      af[mf] = *(const bf16x8*)&smA[(wr * 64 + mf * 16 + li) * 40 + g * 8];
#pragma unroll
    for (int nf = 0; nf < 4; nf++)
      bfr[nf] = *(const bf16x8*)&smB[(wc * 64 + nf * 16 + li) * 40 + g * 8];
#pragma unroll
    for (int mf = 0; mf < 4; mf++)
#pragma unroll
      for (int nf = 0; nf < 4; nf++)
        acc[mf][nf] = MFMA(af[mf], bfr[nf], acc[mf][nf]);
  }

#pragma unroll
  for (int mf = 0; mf < 4; mf++){
    int row = m0 + wr * 64 + mf * 16 + g * 4;
#pragma unroll
    for (int nf = 0; nf < 4; nf++){
      int col = n0 + wc * 64 + nf * 16 + li;
      float bs = bias[col];
#pragma unroll
      for (int r = 0; r < 4; r++){
        float v = acc[mf][nf][r] + bs;
        if (F32OUT) ((float*)outp)[(size_t)(row + r) * N + col] = v;
        else        ((u16*)outp)[(size_t)(row + r) * N + col]  = f2bf(v);
      }
    }
  }
}

// ---------------- RMS (q,k) + scatter into attention layouts ----------------
__global__ __launch_bounds__(256) void rms_scatter(const u16* __restrict__ qkvb, int L,
                                                   const float* __restrict__ gq, const float* __restrict__ gk,
                                                   u16* __restrict__ qdst, int qL, int qoff,
                                                   u16* __restrict__ kdst, int kvoff){
  int tok = blockIdx.x;
  int b = tok / L, l = tok - b * L;
  int t = threadIdx.x;
  int c = t * 4;
  int h = t >> 4;
  int d = c & 63;
  const u16* rowq = qkvb + (size_t)tok * 3072 + c;
  u16x4 qv = *(const u16x4*)rowq;
  u16x4 kv = *(const u16x4*)(rowq + 1024);
  float qf[4], kf[4], ssq = 0.f, ssk = 0.f;
#pragma unroll
  for (int j = 0; j < 4; j++){
    qf[j] = b2f(qv[j]); kf[j] = b2f(kv[j]);
    ssq += qf[j] * qf[j]; ssk += kf[j] * kf[j];
  }
#pragma unroll
  for (int msk = 1; msk < 16; msk <<= 1){
    ssq += __shfl_xor(ssq, msk);
    ssk += __shfl_xor(ssk, msk);
  }
  float sq = 8.0f / fmaxf(sqrtf(ssq), 1e-12f);   // SCALE_RMS = sqrt(64) = 8
  float sk = 8.0f / fmaxf(sqrtf(ssk), 1e-12f);
  u16x4 qo, ko;
#pragma unroll
  for (int j = 0; j < 4; j++){
    qo[j] = f2bf(qf[j] * sq * gq[h * 64 + d + j]);
    ko[j] = f2bf(kf[j] * sk * gk[h * 64 + d + j]);
  }
  *(u16x4*)(qdst + ((size_t)(b * 16 + h) * qL + qoff + l) * 64 + d) = qo;
  *(u16x4*)(kdst + ((size_t)(b * 16 + h) * 3584 + kvoff + l) * 64 + d) = ko;
}

// ---------------- V transpose: qkvb v-part -> vT (B,H,64,3584) ----------------
__global__ __launch_bounds__(256) void vtrans(const u16* __restrict__ qkvb, int L,
                                              u16* __restrict__ vT, int kvoff){
  __shared__ u16 tile[64][65];
  int l0 = blockIdx.x * 64; int h = blockIdx.y; int b = blockIdx.z;
  int t = threadIdx.x;
#pragma unroll
  for (int j = 0; j < 16; j++){
    int idx = j * 256 + t;
    int r = idx >> 6, d = idx & 63;
    tile[r][d] = qkvb[(size_t)(b * L + l0 + r) * 3072 + 2048 + h * 64 + d];
  }
  __syncthreads();
#pragma unroll
  for (int j = 0; j < 16; j++){
    int idx = j * 256 + t;
    int d = idx >> 6, r = idx & 63;
    vT[((size_t)(b * 16 + h) * 64 + d) * 3584 + kvoff + l0 + r] = tile[r][d];
  }
}

// ---------------- flash attention (v3: merged tasks, 2-wave blocks) ----------------
// 2 waves x 32 q-rows = 64 q-rows/block; KV tile = 64; LDS 27.1 KB -> 6 blocks/CU
// (12 waves/CU vs 4.7 in v2 - the round-5 diagnosis was latency-bound at 1.2 w/SIMD).
// Both attentions in ONE launch: blocks [0,768) = joint attn (56 tiles, longest first),
// [768, 1792) = shape self-attn (32 tiles). Within a task: lin = hb + 32*qb keeps all
// qb of one (b,h) on one XCD (same K/V in that XCD's L2; round-5 FETCH confirmed).
__global__ __launch_bounds__(128, 3) void attn(const u16* __restrict__ q0, const u16* __restrict__ q1,
                                               const u16* __restrict__ kmat, const u16* __restrict__ vTm,
                                               u16* __restrict__ ob0, u16* __restrict__ ob1,
                                               u16* __restrict__ ob2){
  __shared__ __align__(16) u16 smK[64 * 72];      // [key][feat]
  __shared__ __align__(16) u16 smV[64 * 72];      // [d][kv]
  __shared__ __align__(16) u16 smP[2][32 * 68];   // per-wave P [qrow][key]
  int lin = blockIdx.x;
  bool t1 = lin < 768;                 // task1 = joint attn (24 qb x 32 hb)
  int rel = t1 ? lin : lin - 768;
  int qb = rel >> 5, hb = rel & 31;
  int h = hb & 15, b = hb >> 4;
  int bh = b * 16 + h;
  const u16* qp = t1 ? q1 : q0;
  int Lq  = t1 ? 1536 : 2048;
  int kvo = t1 ? 0    : 1536;
  int Lk  = t1 ? 3584 : 2048;
  u16* out0 = t1 ? ob1 : ob0;  int L0 = t1 ? 1024 : 2048;
  u16* out1 = t1 ? ob2 : ob0;  int L1 = t1 ? 512  : 2048;

  int t = threadIdx.x, lane = t & 63, w = t >> 6;
  int li = lane & 15, g = lane >> 4;

  // Q fragments: rows qb*64 + w*32 + rb*16 + li
  const u16* qbase = qp + ((size_t)bh * Lq + qb * 64 + w * 32) * 64;
  bf16x8 qa[2][2];
#pragma unroll
  for (int rb = 0; rb < 2; rb++)
#pragma unroll
    for (int kh = 0; kh < 2; kh++)
      qa[rb][kh] = *(const bf16x8*)(qbase + (size_t)(rb * 16 + li) * 64 + kh * 32 + g * 8);

  f32x4 acc[2][4] = {};
  float mrun[2][4], lsum[2][4];
#pragma unroll
  for (int rb = 0; rb < 2; rb++)
#pragma unroll
    for (int r = 0; r < 4; r++){ mrun[rb][r] = -3.0e38f; lsum[rb][r] = 0.f; }

  const u16* kbase = kmat + ((size_t)bh * 3584 + kvo) * 64;
  const u16* vbase = vTm + (size_t)bh * 64 * 3584 + kvo;
  u16* pp = &smP[w][0];

  const float SC = 0.125f * 1.44269504088896340736f;  // SCALE_ATTN * log2(e)

  // staging: 64 rows x 8 x 16B = 512 units over 128 threads -> 4 units each (K and V)
  u16x8 ka[4], va[4];
#pragma unroll
  for (int j = 0; j < 4; j++){
    int u = t + j * 128; int ur = u >> 3, us = (u & 7) * 8;
    ka[j] = *(const u16x8*)(kbase + (size_t)ur * 64 + us);
    va[j] = *(const u16x8*)(vbase + (size_t)ur * 3584 + us);
  }

  for (int kt = 0; kt < Lk; kt += 64){
    __syncthreads();   // prior tile fully consumed by both waves
#pragma unroll
    for (int j = 0; j < 4; j++){
      int u = t + j * 128; int ur = u >> 3, us = (u & 7) * 8;
      *(u16x8*)&smK[ur * 72 + us] = ka[j];
      *(u16x8*)&smV[ur * 72 + us] = va[j];
    }
    __syncthreads();
    if (kt + 64 < Lk){   // prefetch next tile (hides HBM/L2 latency under compute)
#pragma unroll
      for (int j = 0; j < 4; j++){
        int u = t + j * 128; int ur = u >> 3, us = (u & 7) * 8;
        ka[j] = *(const u16x8*)(kbase + (size_t)(kt + 64 + ur) * 64 + us);
        va[j] = *(const u16x8*)(vbase + (size_t)ur * 3584 + kt + 64 + us);
      }
    }

    // ---- S = Q K^T : 32 q-rows x 64 keys ----
    f32x4 s[2][4] = {};
#pragma unroll
    for (int kf = 0; kf < 4; kf++){
      bf16x8 k0 = *(const bf16x8*)&smK[(kf * 16 + li) * 72 + g * 8];
      bf16x8 k1 = *(const bf16x8*)&smK[(kf * 16 + li) * 72 + 32 + g * 8];
      s[0][kf] = MFMA(qa[0][0], k0, s[0][kf]);
      s[0][kf] = MFMA(qa[0][1], k1, s[0][kf]);
      s[1][kf] = MFMA(qa[1][0], k0, s[1][kf]);
      s[1][kf] = MFMA(qa[1][1], k1, s[1][kf]);
    }

    // ---- online softmax (exp2 domain), lane-local partial sums ----
#pragma unroll
    for (int rb = 0; rb < 2; rb++)
#pragma unroll
    for (int r = 0; r < 4; r++){
      float s0 = s[rb][0][r] * SC, s1 = s[rb][1][r] * SC;
      float s2 = s[rb][2][r] * SC, s3 = s[rb][3][r] * SC;
      float rm = fmaxf(fmaxf(s0, s1), fmaxf(s2, s3));
#pragma unroll
      for (int msk = 1; msk < 16; msk <<= 1) rm = fmaxf(rm, __shfl_xor(rm, msk));
      float mo = mrun[rb][r];
      float mn = fmaxf(mo, rm);
      float al = __builtin_exp2f(mo - mn);
      mrun[rb][r] = mn;
      float p0 = __builtin_exp2f(s0 - mn), p1 = __builtin_exp2f(s1 - mn);
      float p2 = __builtin_exp2f(s2 - mn), p3 = __builtin_exp2f(s3 - mn);
      lsum[rb][r] = lsum[rb][r] * al + (p0 + p1) + (p2 + p3);
#pragma unroll
      for (int dt = 0; dt < 4; dt++) acc[rb][dt][r] *= al;
      int row = rb * 16 + g * 4 + r;
      pp[row * 68 + li]      = f2bf(p0);
      pp[row * 68 + 16 + li] = f2bf(p1);
      pp[row * 68 + 32 + li] = f2bf(p2);
      pp[row * 68 + 48 + li] = f2bf(p3);
    }

    // ---- O += P V ----
    bf16x8 vf[4][2];
#pragma unroll
    for (int dt = 0; dt < 4; dt++){
      vf[dt][0] = *(const bf16x8*)&smV[(dt * 16 + li) * 72 + g * 8];
      vf[dt][1] = *(const bf16x8*)&smV[(dt * 16 + li) * 72 + 32 + g * 8];
    }
#pragma unroll
    for (int rb = 0; rb < 2; rb++){
      bf16x8 pf0 = *(const bf16x8*)&pp[(rb * 16 + li) * 68 + g * 8];
      bf16x8 pf1 = *(const bf16x8*)&pp[(rb * 16 + li) * 68 + 32 + g * 8];
#pragma unroll
      for (int dt = 0; dt < 4; dt++){
        acc[rb][dt] = MFMA(pf0, vf[dt][0], acc[rb][dt]);
        acc[rb][dt] = MFMA(pf1, vf[dt][1], acc[rb][dt]);
      }
    }
  }

  // ---- epilogue: reduce partial sums, normalize, scatter ----
#pragma unroll
  for (int rb = 0; rb < 2; rb++)
#pragma unroll
  for (int r = 0; r < 4; r++){
    float ls = lsum[rb][r];
#pragma unroll
    for (int msk = 1; msk < 16; msk <<= 1) ls += __shfl_xor(ls, msk);
    float inv = 1.0f / ls;
    int qi = qb * 64 + w * 32 + rb * 16 + g * 4 + r;
    u16* dst; size_t basei;
    if (qi < L0){ dst = out0; basei = ((size_t)(b * L0 + qi)) * 1024 + h * 64; }
    else        { dst = out1; basei = ((size_t)(b * L1 + (qi - L0))) * 1024 + h * 64; }
#pragma unroll
    for (int dt = 0; dt < 4; dt++)
      dst[basei + dt * 16 + li] = f2bf(acc[rb][dt][r] * inv);
  }
}

// ---------------- launch ----------------
extern "C" void kernel_launch(void* const* d_in, const int* in_sizes, int n_in,
                              void* d_out, int out_size, void* d_ws, size_t ws_size,
                              hipStream_t stream){
  (void)in_sizes; (void)n_in; (void)out_size; (void)ws_size;
  const float* x[3]    = {(const float*)d_in[0],  (const float*)d_in[7],  (const float*)d_in[14]};
  const float* Wqkv[3] = {(const float*)d_in[1],  (const float*)d_in[8],  (const float*)d_in[15]};
  const float* bqkv[3] = {(const float*)d_in[2],  (const float*)d_in[9],  (const float*)d_in[16]};
  const float* gq[3]   = {(const float*)d_in[3],  (const float*)d_in[10], (const float*)d_in[17]};
  const float* gk[3]   = {(const float*)d_in[4],  (const float*)d_in[11], (const float*)d_in[18]};
  const float* Wout[3] = {(const float*)d_in[5],  (const float*)d_in[12], (const float*)d_in[19]};
  const float* bout[3] = {(const float*)d_in[6],  (const float*)d_in[13], (const float*)d_in[20]};
  float* outp = (float*)d_out;

  const int Ms[3] = {4096, 2048, 1024};   // B*L per modality
  const int Ls[3] = {2048, 1024, 512};
  const int kvoffs[3] = {1536, 0, 1024};  // joint KV order: [texture, color, shape]

  u16* base = (u16*)d_ws;
  size_t off = 0;
  auto nxt = [&](size_t e){ u16* r = base + off; off += e; return r; };
  u16* xbf[3];  for (int m = 0; m < 3; m++) xbf[m]  = nxt((size_t)Ms[m] * 1024);
  u16* WqT[3];  for (int m = 0; m < 3; m++) WqT[m]  = nxt((size_t)3072 * 1024);
  u16* WoT[3];  for (int m = 0; m < 3; m++) WoT[m]  = nxt((size_t)1024 * 1024);
  u16* qkvb[3]; for (int m = 0; m < 3; m++) qkvb[m] = nxt((size_t)Ms[m] * 3072);
  u16* qA = nxt((size_t)2 * 16 * 2048 * 64);
  u16* qB = nxt((size_t)2 * 16 * 1536 * 64);
  u16* kB = nxt((size_t)2 * 16 * 3584 * 64);
  // aliases (disjoint lifetimes, stream-ordered):
  u16* vT = WqT[0];                        // vT reuses WqT block: WqT dead after QKV GEMMs
  u16* hb[3]; for (int m = 0; m < 3; m++) hb[m] = xbf[m];  // xbf dead after QKV GEMMs

  // 1) conversions
  for (int m = 0; m < 3; m++){
    int n4 = Ms[m] * 1024 / 4;
    cvt_f32_bf16<<<n4 / 256, 256, 0, stream>>>(x[m], xbf[m], n4);
    tcvt<<<dim3(3072 / 64, 1024 / 64), 256, 0, stream>>>(Wqkv[m], WqT[m], 1024, 3072);
    tcvt<<<dim3(1024 / 64, 1024 / 64), 256, 0, stream>>>(Wout[m], WoT[m], 1024, 1024);
  }
  // 2) qkv projections
  for (int m = 0; m < 3; m++)
    gemm_bt<0><<<dim3(3072 / 128, Ms[m] / 128), 256, 0, stream>>>(
        xbf[m], WqT[m], bqkv[m], qkvb[m], Ms[m], 3072, 1024);
  // 3) RMS + scatter q/k ; transpose v
  rms_scatter<<<Ms[0], 256, 0, stream>>>(qkvb[0], Ls[0], gq[0], gk[0], qA, 2048, 0,    kB, 1536);
  rms_scatter<<<Ms[1], 256, 0, stream>>>(qkvb[1], Ls[1], gq[1], gk[1], qB, 1536, 0,    kB, 0);
  rms_scatter<<<Ms[2], 256, 0, stream>>>(qkvb[2], Ls[2], gq[2], gk[2], qB, 1536, 1024, kB, 1024);
  for (int m = 0; m < 3; m++)
    vtrans<<<dim3(Ls[m] / 64, 16, 2), 256, 0, stream>>>(qkvb[m], Ls[m], vT, kvoffs[m]);
  // 4) both attentions, single launch: 768 joint-attn blocks + 1024 self-attn blocks
  attn<<<1792, 128, 0, stream>>>(qA, qB, kB, vT, hb[0], hb[1], hb[2]);
  // 5) output projections
  float* outs[3] = {outp, outp + (size_t)4096 * 1024, outp + (size_t)6144 * 1024};
  for (int m = 0; m < 3; m++)
    gemm_bt<1><<<dim3(1024 / 128, Ms[m] / 128), 256, 0, stream>>>(
        hb[m], WoT[m], bout[m], outs[m], Ms[m], 1024, 1024);
}

// Round 7
// 563.924 us; speedup vs baseline: 1.2718x; 1.1803x over previous
//
#include <hip/hip_runtime.h>
#include <hip/hip_bf16.h>
#include <stdint.h>

typedef unsigned short u16;
typedef __attribute__((ext_vector_type(8))) short bf16x8;   // 8 bf16 (4 VGPRs), per guide §3
typedef __attribute__((ext_vector_type(4))) float f32x4;
typedef __attribute__((ext_vector_type(4))) unsigned short u16x4;
typedef __attribute__((ext_vector_type(8))) unsigned short u16x8;

#define DEV __device__ __forceinline__

DEV u16 f2bf(float f){ // round-to-nearest-even f32 -> bf16
  unsigned u = __float_as_uint(f);
  return (u16)((u + 0x7FFFu + ((u >> 16) & 1u)) >> 16);
}
DEV float b2f(u16 v){ return __uint_as_float(((unsigned)v) << 16); }

DEV f32x4 MFMA(bf16x8 a, bf16x8 b, f32x4 c){
  // D = A*B + C ; a = rows of A (M,K), b = rows of B^T (N,K) -> computes A·B
  return __builtin_amdgcn_mfma_f32_16x16x32_bf16(a, b, c, 0, 0, 0);
}

// ---------------- elementwise f32 -> bf16 ----------------
__global__ __launch_bounds__(256) void cvt_f32_bf16(const float* __restrict__ in,
                                                    u16* __restrict__ out, int n4){
  int i = blockIdx.x * 256 + threadIdx.x;
  if (i >= n4) return;
  f32x4 v = ((const f32x4*)in)[i];
  u16x4 o;
  o[0] = f2bf(v[0]); o[1] = f2bf(v[1]); o[2] = f2bf(v[2]); o[3] = f2bf(v[3]);
  ((u16x4*)out)[i] = o;
}

// ---------------- transpose + convert: out[c][r] = bf16(in[r][c]) ----------------
__global__ __launch_bounds__(256) void tcvt(const float* __restrict__ in, u16* __restrict__ out,
                                            int R, int C){
  __shared__ float tile[64][65];
  int c0 = blockIdx.x * 64, r0 = blockIdx.y * 64;
  int t = threadIdx.x;
#pragma unroll
  for (int j = 0; j < 16; j++){
    int idx = j * 256 + t;
    int r = idx >> 6, c = idx & 63;
    tile[r][c] = in[(size_t)(r0 + r) * C + c0 + c];
  }
  __syncthreads();
#pragma unroll
  for (int j = 0; j < 16; j++){
    int idx = j * 256 + t;
    int c = idx >> 6, r = idx & 63;
    out[(size_t)(c0 + c) * R + r0 + r] = f2bf(tile[r][c]);
  }
}

// ---------------- GEMM: out(M,N) = A(M,K) * Bt(N,K)^T + bias ----------------
// 128x128 tile, BK=32, 4 waves (2x2), 4x4 16x16 frags per wave (m93-structure).
template<int F32OUT>
__global__ __launch_bounds__(256) void gemm_bt(const u16* __restrict__ A, const u16* __restrict__ Bt,
                                               const float* __restrict__ bias, void* __restrict__ outp,
                                               int M, int N, int K){
  __shared__ __align__(16) u16 smA[128 * 40];
  __shared__ __align__(16) u16 smB[128 * 40];
  int t = threadIdx.x;
  int lane = t & 63, w = t >> 6;
  int wr = w >> 1, wc = w & 1;
  int li = lane & 15, g = lane >> 4;
  int m0 = blockIdx.y * 128, n0 = blockIdx.x * 128;

  int srow = t >> 2, sseg = (t & 3) * 8;          // staging: 64 rows x 4 x 16B
  const u16* Ap0 = A  + (size_t)(m0 + srow) * K + sseg;
  const u16* Ap1 = Ap0 + (size_t)64 * K;
  const u16* Bp0 = Bt + (size_t)(n0 + srow) * K + sseg;
  const u16* Bp1 = Bp0 + (size_t)64 * K;

  f32x4 acc[4][4] = {};
  u16x8 a0 = *(const u16x8*)Ap0, a1 = *(const u16x8*)Ap1;
  u16x8 b0 = *(const u16x8*)Bp0, b1 = *(const u16x8*)Bp1;

  for (int kt = 32; kt <= K; kt += 32){
    __syncthreads();
    *(u16x8*)&smA[srow * 40 + sseg]        = a0;
    *(u16x8*)&smA[(64 + srow) * 40 + sseg] = a1;
    *(u16x8*)&smB[srow * 40 + sseg]        = b0;
    *(u16x8*)&smB[(64 + srow) * 40 + sseg] = b1;
    __syncthreads();
    if (kt < K){
      a0 = *(const u16x8*)(Ap0 + kt); a1 = *(const u16x8*)(Ap1 + kt);
      b0 = *(const u16x8*)(Bp0 + kt); b1 = *(const u16x8*)(Bp1 + kt);
    }
    bf16x8 af[4], bfr[4];
#pragma unroll
    for (int mf = 0; mf < 4; mf++)
      af[mf] = *(const bf16x8*)&smA[(wr * 64 + mf * 16 + li) * 40 + g * 8];
#pragma unroll
    for (int nf = 0; nf < 4; nf++)
      bfr[nf] = *(const bf16x8*)&smB[(wc * 64 + nf * 16 + li) * 40 + g * 8];
#pragma unroll
    for (int mf = 0; mf < 4; mf++)
#pragma unroll
      for (int nf = 0; nf < 4; nf++)
        acc[mf][nf] = MFMA(af[mf], bfr[nf], acc[mf][nf]);
  }

#pragma unroll
  for (int mf = 0; mf < 4; mf++){
    int row = m0 + wr * 64 + mf * 16 + g * 4;
#pragma unroll
    for (int nf = 0; nf < 4; nf++){
      int col = n0 + wc * 64 + nf * 16 + li;
      float bs = bias[col];
#pragma unroll
      for (int r = 0; r < 4; r++){
        float v = acc[mf][nf][r] + bs;
        if (F32OUT) ((float*)outp)[(size_t)(row + r) * N + col] = v;
        else        ((u16*)outp)[(size_t)(row + r) * N + col]  = f2bf(v);
      }
    }
  }
}

// ---------------- RMS (q,k) + scatter into attention layouts ----------------
__global__ __launch_bounds__(256) void rms_scatter(const u16* __restrict__ qkvb, int L,
                                                   const float* __restrict__ gq, const float* __restrict__ gk,
                                                   u16* __restrict__ qdst, int qL, int qoff,
                                                   u16* __restrict__ kdst, int kvoff){
  int tok = blockIdx.x;
  int b = tok / L, l = tok - b * L;
  int t = threadIdx.x;
  int c = t * 4;
  int h = t >> 4;
  int d = c & 63;
  const u16* rowq = qkvb + (size_t)tok * 3072 + c;
  u16x4 qv = *(const u16x4*)rowq;
  u16x4 kv = *(const u16x4*)(rowq + 1024);
  float qf[4], kf[4], ssq = 0.f, ssk = 0.f;
#pragma unroll
  for (int j = 0; j < 4; j++){
    qf[j] = b2f(qv[j]); kf[j] = b2f(kv[j]);
    ssq += qf[j] * qf[j]; ssk += kf[j] * kf[j];
  }
#pragma unroll
  for (int msk = 1; msk < 16; msk <<= 1){
    ssq += __shfl_xor(ssq, msk);
    ssk += __shfl_xor(ssk, msk);
  }
  float sq = 8.0f / fmaxf(sqrtf(ssq), 1e-12f);   // SCALE_RMS = sqrt(64) = 8
  float sk = 8.0f / fmaxf(sqrtf(ssk), 1e-12f);
  u16x4 qo, ko;
#pragma unroll
  for (int j = 0; j < 4; j++){
    qo[j] = f2bf(qf[j] * sq * gq[h * 64 + d + j]);
    ko[j] = f2bf(kf[j] * sk * gk[h * 64 + d + j]);
  }
  *(u16x4*)(qdst + ((size_t)(b * 16 + h) * qL + qoff + l) * 64 + d) = qo;
  *(u16x4*)(kdst + ((size_t)(b * 16 + h) * 3584 + kvoff + l) * 64 + d) = ko;
}

// ---------------- V transpose: qkvb v-part -> vT (B,H,64,3584) ----------------
__global__ __launch_bounds__(256) void vtrans(const u16* __restrict__ qkvb, int L,
                                              u16* __restrict__ vT, int kvoff){
  __shared__ u16 tile[64][65];
  int l0 = blockIdx.x * 64; int h = blockIdx.y; int b = blockIdx.z;
  int t = threadIdx.x;
#pragma unroll
  for (int j = 0; j < 16; j++){
    int idx = j * 256 + t;
    int r = idx >> 6, d = idx & 63;
    tile[r][d] = qkvb[(size_t)(b * L + l0 + r) * 3072 + 2048 + h * 64 + d];
  }
  __syncthreads();
#pragma unroll
  for (int j = 0; j < 16; j++){
    int idx = j * 256 + t;
    int d = idx >> 6, r = idx & 63;
    vT[((size_t)(b * 16 + h) * 64 + d) * 3584 + kvoff + l0 + r] = tile[r][d];
  }
}

// ---------------- flash attention (v4: swapped QK^T, lane-local softmax) ----------------
// S^T = K·Q^T so lane li owns q-row li (C/D: col=li, row=g*4+r per m89): row-max is a
// register fmax tree + 2 shfl (vs 32 bpermutes in v3); m/l are per-lane scalars; PV is
// swapped too (O^T = V^T·P^T) so rescale/normalize are lane-local. Same staging/LDS/MFMA
// count as v3. 2 waves x 32 q-rows; KVBLK=64; merged tasks (768 joint + 1024 self blocks).
__global__ __launch_bounds__(128, 3) void attn(const u16* __restrict__ q0, const u16* __restrict__ q1,
                                               const u16* __restrict__ kmat, const u16* __restrict__ vTm,
                                               u16* __restrict__ ob0, u16* __restrict__ ob1,
                                               u16* __restrict__ ob2){
  __shared__ __align__(16) u16 smK[64 * 72];      // [key][feat]
  __shared__ __align__(16) u16 smV[64 * 72];      // [d][kv]
  __shared__ __align__(16) u16 smP[2][32 * 68];   // per-wave P [qrow][key]
  int lin = blockIdx.x;
  bool t1 = lin < 768;                 // task1 = joint attn (24 qb x 32 hb)
  int rel = t1 ? lin : lin - 768;
  int qb = rel >> 5, hb = rel & 31;
  int h = hb & 15, b = hb >> 4;
  int bh = b * 16 + h;
  const u16* qp = t1 ? q1 : q0;
  int Lq  = t1 ? 1536 : 2048;
  int kvo = t1 ? 0    : 1536;
  int Lk  = t1 ? 3584 : 2048;
  u16* out0 = t1 ? ob1 : ob0;  int L0 = t1 ? 1024 : 2048;
  u16* out1 = t1 ? ob2 : ob0;  int L1 = t1 ? 512  : 2048;

  int t = threadIdx.x, lane = t & 63, w = t >> 6;
  int li = lane & 15, g = lane >> 4;

  // Q fragments: rows qb*64 + w*32 + qg*16 + li
  const u16* qbase = qp + ((size_t)bh * Lq + qb * 64 + w * 32) * 64;
  bf16x8 qa[2][2];
#pragma unroll
  for (int qg = 0; qg < 2; qg++)
#pragma unroll
    for (int kh = 0; kh < 2; kh++)
      qa[qg][kh] = *(const bf16x8*)(qbase + (size_t)(qg * 16 + li) * 64 + kh * 32 + g * 8);

  // acc[qg][dt] = O^T fragment: lane li = q-row qg*16+li, values d = dt*16 + g*4 + r
  f32x4 acc[2][4] = {};
  float mrunL[2] = {-3.0e38f, -3.0e38f};
  float lsumL[2] = {0.f, 0.f};   // per-lane partial over this lane's 16 keys/tile

  const u16* kbase = kmat + ((size_t)bh * 3584 + kvo) * 64;
  const u16* vbase = vTm + (size_t)bh * 64 * 3584 + kvo;
  u16* pp = &smP[w][0];

  const float SC = 0.125f * 1.44269504088896340736f;  // SCALE_ATTN * log2(e)

  // staging: 64 rows x 8 x 16B = 512 units over 128 threads -> 4 units each (K and V)
  u16x8 ka[4], va[4];
#pragma unroll
  for (int j = 0; j < 4; j++){
    int u = t + j * 128; int ur = u >> 3, us = (u & 7) * 8;
    ka[j] = *(const u16x8*)(kbase + (size_t)ur * 64 + us);
    va[j] = *(const u16x8*)(vbase + (size_t)ur * 3584 + us);
  }

  for (int kt = 0; kt < Lk; kt += 64){
    __syncthreads();   // prior tile fully consumed by both waves
#pragma unroll
    for (int j = 0; j < 4; j++){
      int u = t + j * 128; int ur = u >> 3, us = (u & 7) * 8;
      *(u16x8*)&smK[ur * 72 + us] = ka[j];
      *(u16x8*)&smV[ur * 72 + us] = va[j];
    }
    __syncthreads();
    if (kt + 64 < Lk){   // prefetch next tile (hides HBM/L2 latency under compute)
#pragma unroll
      for (int j = 0; j < 4; j++){
        int u = t + j * 128; int ur = u >> 3, us = (u & 7) * 8;
        ka[j] = *(const u16x8*)(kbase + (size_t)(kt + 64 + ur) * 64 + us);
        va[j] = *(const u16x8*)(vbase + (size_t)ur * 3584 + kt + 64 + us);
      }
    }

    // ---- S^T = K Q^T : lane li holds q-row li, keys kg*16 + g*4 + r ----
    f32x4 sT[2][4];   // [qg][kg]
#pragma unroll
    for (int kg = 0; kg < 4; kg++){
      bf16x8 kf0 = *(const bf16x8*)&smK[(kg * 16 + li) * 72 + g * 8];
      bf16x8 kf1 = *(const bf16x8*)&smK[(kg * 16 + li) * 72 + 32 + g * 8];
#pragma unroll
      for (int qg = 0; qg < 2; qg++){
        f32x4 z = {};
        z = MFMA(kf0, qa[qg][0], z);
        sT[qg][kg] = MFMA(kf1, qa[qg][1], z);
      }
    }

    // ---- online softmax: register tree + 2 shfl for max; everything else lane-local ----
#pragma unroll
    for (int qg = 0; qg < 2; qg++){
      float sc[16];
#pragma unroll
      for (int kg = 0; kg < 4; kg++)
#pragma unroll
        for (int r = 0; r < 4; r++) sc[kg * 4 + r] = sT[qg][kg][r] * SC;
      float m01 = fmaxf(fmaxf(sc[0], sc[1]),   fmaxf(sc[2], sc[3]));
      float m23 = fmaxf(fmaxf(sc[4], sc[5]),   fmaxf(sc[6], sc[7]));
      float m45 = fmaxf(fmaxf(sc[8], sc[9]),   fmaxf(sc[10], sc[11]));
      float m67 = fmaxf(fmaxf(sc[12], sc[13]), fmaxf(sc[14], sc[15]));
      float rm = fmaxf(fmaxf(m01, m23), fmaxf(m45, m67));
      rm = fmaxf(rm, __shfl_xor(rm, 16));   // reduce across the 4 g-lanes of this q-row
      rm = fmaxf(rm, __shfl_xor(rm, 32));
      float mo = mrunL[qg];
      float mn = fmaxf(mo, rm);
      float al = __builtin_exp2f(mo - mn);
      mrunL[qg] = mn;
      float ps = 0.f;
      u16x4 pk[4];
#pragma unroll
      for (int kg = 0; kg < 4; kg++){
#pragma unroll
        for (int r = 0; r < 4; r++){
          float p = __builtin_exp2f(sc[kg * 4 + r] - mn);
          ps += p;
          pk[kg][r] = f2bf(p);
        }
      }
      lsumL[qg] = lsumL[qg] * al + ps;
#pragma unroll
      for (int dt = 0; dt < 4; dt++)
#pragma unroll
        for (int r = 0; r < 4; r++) acc[qg][dt][r] *= al;
      // store P[qrow qg*16+li][keys kg*16+g*4 .. +3]
#pragma unroll
      for (int kg = 0; kg < 4; kg++)
        *(u16x4*)&pp[(qg * 16 + li) * 68 + kg * 16 + g * 4] = pk[kg];
    }

    // ---- O^T += V^T P^T : acc lane li = q-row li ----
    bf16x8 pf[2][2];
#pragma unroll
    for (int qg = 0; qg < 2; qg++){
      pf[qg][0] = *(const bf16x8*)&pp[(qg * 16 + li) * 68 + g * 8];
      pf[qg][1] = *(const bf16x8*)&pp[(qg * 16 + li) * 68 + 32 + g * 8];
    }
#pragma unroll
    for (int dt = 0; dt < 4; dt++){
      bf16x8 vf0 = *(const bf16x8*)&smV[(dt * 16 + li) * 72 + g * 8];
      bf16x8 vf1 = *(const bf16x8*)&smV[(dt * 16 + li) * 72 + 32 + g * 8];
#pragma unroll
      for (int qg = 0; qg < 2; qg++){
        acc[qg][dt] = MFMA(vf0, pf[qg][0], acc[qg][dt]);
        acc[qg][dt] = MFMA(vf1, pf[qg][1], acc[qg][dt]);
      }
    }
  }

  // ---- epilogue: 2-shfl sum reduce, lane-local normalize, u16x4 stores ----
#pragma unroll
  for (int qg = 0; qg < 2; qg++){
    float ls = lsumL[qg];
    ls += __shfl_xor(ls, 16);
    ls += __shfl_xor(ls, 32);
    float inv = 1.0f / ls;
    int qi = qb * 64 + w * 32 + qg * 16 + li;
    u16* dst; size_t basei;
    if (qi < L0){ dst = out0; basei = ((size_t)(b * L0 + qi)) * 1024 + h * 64; }
    else        { dst = out1; basei = ((size_t)(b * L1 + (qi - L0))) * 1024 + h * 64; }
#pragma unroll
    for (int dt = 0; dt < 4; dt++){
      u16x4 o;
#pragma unroll
      for (int r = 0; r < 4; r++) o[r] = f2bf(acc[qg][dt][r] * inv);
      *(u16x4*)&dst[basei + dt * 16 + g * 4] = o;
    }
  }
}

// ---------------- launch ----------------
extern "C" void kernel_launch(void* const* d_in, const int* in_sizes, int n_in,
                              void* d_out, int out_size, void* d_ws, size_t ws_size,
                              hipStream_t stream){
  (void)in_sizes; (void)n_in; (void)out_size; (void)ws_size;
  const float* x[3]    = {(const float*)d_in[0],  (const float*)d_in[7],  (const float*)d_in[14]};
  const float* Wqkv[3] = {(const float*)d_in[1],  (const float*)d_in[8],  (const float*)d_in[15]};
  const float* bqkv[3] = {(const float*)d_in[2],  (const float*)d_in[9],  (const float*)d_in[16]};
  const float* gq[3]   = {(const float*)d_in[3],  (const float*)d_in[10], (const float*)d_in[17]};
  const float* gk[3]   = {(const float*)d_in[4],  (const float*)d_in[11], (const float*)d_in[18]};
  const float* Wout[3] = {(const float*)d_in[5],  (const float*)d_in[12], (const float*)d_in[19]};
  const float* bout[3] = {(const float*)d_in[6],  (const float*)d_in[13], (const float*)d_in[20]};
  float* outp = (float*)d_out;

  const int Ms[3] = {4096, 2048, 1024};   // B*L per modality
  const int Ls[3] = {2048, 1024, 512};
  const int kvoffs[3] = {1536, 0, 1024};  // joint KV order: [texture, color, shape]

  u16* base = (u16*)d_ws;
  size_t off = 0;
  auto nxt = [&](size_t e){ u16* r = base + off; off += e; return r; };
  u16* xbf[3];  for (int m = 0; m < 3; m++) xbf[m]  = nxt((size_t)Ms[m] * 1024);
  u16* WqT[3];  for (int m = 0; m < 3; m++) WqT[m]  = nxt((size_t)3072 * 1024);
  u16* WoT[3];  for (int m = 0; m < 3; m++) WoT[m]  = nxt((size_t)1024 * 1024);
  u16* qkvb[3]; for (int m = 0; m < 3; m++) qkvb[m] = nxt((size_t)Ms[m] * 3072);
  u16* qA = nxt((size_t)2 * 16 * 2048 * 64);
  u16* qB = nxt((size_t)2 * 16 * 1536 * 64);
  u16* kB = nxt((size_t)2 * 16 * 3584 * 64);
  // aliases (disjoint lifetimes, stream-ordered):
  u16* vT = WqT[0];                        // vT reuses WqT block: WqT dead after QKV GEMMs
  u16* hb[3]; for (int m = 0; m < 3; m++) hb[m] = xbf[m];  // xbf dead after QKV GEMMs

  // 1) conversions
  for (int m = 0; m < 3; m++){
    int n4 = Ms[m] * 1024 / 4;
    cvt_f32_bf16<<<n4 / 256, 256, 0, stream>>>(x[m], xbf[m], n4);
    tcvt<<<dim3(3072 / 64, 1024 / 64), 256, 0, stream>>>(Wqkv[m], WqT[m], 1024, 3072);
    tcvt<<<dim3(1024 / 64, 1024 / 64), 256, 0, stream>>>(Wout[m], WoT[m], 1024, 1024);
  }
  // 2) qkv projections
  for (int m = 0; m < 3; m++)
    gemm_bt<0><<<dim3(3072 / 128, Ms[m] / 128), 256, 0, stream>>>(
        xbf[m], WqT[m], bqkv[m], qkvb[m], Ms[m], 3072, 1024);
  // 3) RMS + scatter q/k ; transpose v
  rms_scatter<<<Ms[0], 256, 0, stream>>>(qkvb[0], Ls[0], gq[0], gk[0], qA, 2048, 0,    kB, 1536);
  rms_scatter<<<Ms[1], 256, 0, stream>>>(qkvb[1], Ls[1], gq[1], gk[1], qB, 1536, 0,    kB, 0);
  rms_scatter<<<Ms[2], 256, 0, stream>>>(qkvb[2], Ls[2], gq[2], gk[2], qB, 1536, 1024, kB, 1024);
  for (int m = 0; m < 3; m++)
    vtrans<<<dim3(Ls[m] / 64, 16, 2), 256, 0, stream>>>(qkvb[m], Ls[m], vT, kvoffs[m]);
  // 4) both attentions, single launch: 768 joint-attn blocks + 1024 self-attn blocks
  attn<<<1792, 128, 0, stream>>>(qA, qB, kB, vT, hb[0], hb[1], hb[2]);
  // 5) output projections
  float* outs[3] = {outp, outp + (size_t)4096 * 1024, outp + (size_t)6144 * 1024};
  for (int m = 0; m < 3; m++)
    gemm_bt<1><<<dim3(1024 / 128, Ms[m] / 128), 256, 0, stream>>>(
        hb[m], WoT[m], bout[m], outs[m], Ms[m], 1024, 1024);
}

// Round 9
// 542.432 us; speedup vs baseline: 1.3222x; 1.0396x over previous
//
#include <hip/hip_runtime.h>
#include <hip/hip_bf16.h>
#include <stdint.h>

typedef unsigned short u16;
typedef unsigned int u32;
typedef __attribute__((ext_vector_type(8))) short bf16x8;   // 8 bf16 (4 VGPRs), per guide §3
typedef __attribute__((ext_vector_type(4))) float f32x4;
typedef __attribute__((ext_vector_type(2))) unsigned int u32x2;
typedef __attribute__((ext_vector_type(4))) unsigned short u16x4;
typedef __attribute__((ext_vector_type(8))) unsigned short u16x8;

#define DEV __device__ __forceinline__

DEV u16 f2bf(float f){ // round-to-nearest-even f32 -> bf16
  unsigned u = __float_as_uint(f);
  return (u16)((u + 0x7FFFu + ((u >> 16) & 1u)) >> 16);
}
DEV float b2f(u16 v){ return __uint_as_float(((unsigned)v) << 16); }

DEV u32 cvtpk(float lo, float hi){  // packed f32x2 -> bf16x2 (RNE), 1 instr (T12)
  u32 r;
  asm("v_cvt_pk_bf16_f32 %0, %1, %2" : "=v"(r) : "v"(lo), "v"(hi));
  return r;
}

DEV f32x4 MFMA(bf16x8 a, bf16x8 b, f32x4 c){
  // D = A*B + C ; a = rows of A (M,K), b = rows of B^T (N,K) -> computes A·B
  return __builtin_amdgcn_mfma_f32_16x16x32_bf16(a, b, c, 0, 0, 0);
}

// ---------------- elementwise f32 -> bf16 ----------------
__global__ __launch_bounds__(256) void cvt_f32_bf16(const float* __restrict__ in,
                                                    u16* __restrict__ out, int n4){
  int i = blockIdx.x * 256 + threadIdx.x;
  if (i >= n4) return;
  f32x4 v = ((const f32x4*)in)[i];
  u16x4 o;
  o[0] = f2bf(v[0]); o[1] = f2bf(v[1]); o[2] = f2bf(v[2]); o[3] = f2bf(v[3]);
  ((u16x4*)out)[i] = o;
}

// ---------------- transpose + convert: out[c][r] = bf16(in[r][c]) ----------------
__global__ __launch_bounds__(256) void tcvt(const float* __restrict__ in, u16* __restrict__ out,
                                            int R, int C){
  __shared__ float tile[64][65];
  int c0 = blockIdx.x * 64, r0 = blockIdx.y * 64;
  int t = threadIdx.x;
#pragma unroll
  for (int j = 0; j < 16; j++){
    int idx = j * 256 + t;
    int r = idx >> 6, c = idx & 63;
    tile[r][c] = in[(size_t)(r0 + r) * C + c0 + c];
  }
  __syncthreads();
#pragma unroll
  for (int j = 0; j < 16; j++){
    int idx = j * 256 + t;
    int c = idx >> 6, r = idx & 63;
    out[(size_t)(c0 + c) * R + r0 + r] = f2bf(tile[r][c]);
  }
}

// ---------------- GEMM: out(M,N) = A(M,K) * Bt(N,K)^T + bias ----------------
// 128x128 tile, BK=32, 4 waves (2x2), 4x4 16x16 frags per wave (m93-structure).
template<int F32OUT>
__global__ __launch_bounds__(256) void gemm_bt(const u16* __restrict__ A, const u16* __restrict__ Bt,
                                               const float* __restrict__ bias, void* __restrict__ outp,
                                               int M, int N, int K){
  __shared__ __align__(16) u16 smA[128 * 40];
  __shared__ __align__(16) u16 smB[128 * 40];
  int t = threadIdx.x;
  int lane = t & 63, w = t >> 6;
  int wr = w >> 1, wc = w & 1;
  int li = lane & 15, g = lane >> 4;
  int m0 = blockIdx.y * 128, n0 = blockIdx.x * 128;

  int srow = t >> 2, sseg = (t & 3) * 8;          // staging: 64 rows x 4 x 16B
  const u16* Ap0 = A  + (size_t)(m0 + srow) * K + sseg;
  const u16* Ap1 = Ap0 + (size_t)64 * K;
  const u16* Bp0 = Bt + (size_t)(n0 + srow) * K + sseg;
  const u16* Bp1 = Bp0 + (size_t)64 * K;

  f32x4 acc[4][4] = {};
  u16x8 a0 = *(const u16x8*)Ap0, a1 = *(const u16x8*)Ap1;
  u16x8 b0 = *(const u16x8*)Bp0, b1 = *(const u16x8*)Bp1;

  for (int kt = 32; kt <= K; kt += 32){
    __syncthreads();
    *(u16x8*)&smA[srow * 40 + sseg]        = a0;
    *(u16x8*)&smA[(64 + srow) * 40 + sseg] = a1;
    *(u16x8*)&smB[srow * 40 + sseg]        = b0;
    *(u16x8*)&smB[(64 + srow) * 40 + sseg] = b1;
    __syncthreads();
    if (kt < K){
      a0 = *(const u16x8*)(Ap0 + kt); a1 = *(const u16x8*)(Ap1 + kt);
      b0 = *(const u16x8*)(Bp0 + kt); b1 = *(const u16x8*)(Bp1 + kt);
    }
    bf16x8 af[4], bfr[4];
#pragma unroll
    for (int mf = 0; mf < 4; mf++)
      af[mf] = *(const bf16x8*)&smA[(wr * 64 + mf * 16 + li) * 40 + g * 8];
#pragma unroll
    for (int nf = 0; nf < 4; nf++)
      bfr[nf] = *(const bf16x8*)&smB[(wc * 64 + nf * 16 + li) * 40 + g * 8];
#pragma unroll
    for (int mf = 0; mf < 4; mf++)
#pragma unroll
      for (int nf = 0; nf < 4; nf++)
        acc[mf][nf] = MFMA(af[mf], bfr[nf], acc[mf][nf]);
  }

#pragma unroll
  for (int mf = 0; mf < 4; mf++){
    int row = m0 + wr * 64 + mf * 16 + g * 4;
#pragma unroll
    for (int nf = 0; nf < 4; nf++){
      int col = n0 + wc * 64 + nf * 16 + li;
      float bs = bias[col];
#pragma unroll
      for (int r = 0; r < 4; r++){
        float v = acc[mf][nf][r] + bs;
        if (F32OUT) ((float*)outp)[(size_t)(row + r) * N + col] = v;
        else        ((u16*)outp)[(size_t)(row + r) * N + col]  = f2bf(v);
      }
    }
  }
}

// ---------------- RMS (q,k) + scatter into attention layouts ----------------
// q is PRE-SCALED by SCALE_RMS*SCALE_ATTN*log2(e) = log2(e): QK^T lands in exp2 domain.
__global__ __launch_bounds__(256) void rms_scatter(const u16* __restrict__ qkvb, int L,
                                                   const float* __restrict__ gq, const float* __restrict__ gk,
                                                   u16* __restrict__ qdst, int qL, int qoff,
                                                   u16* __restrict__ kdst, int kvoff){
  int tok = blockIdx.x;
  int b = tok / L, l = tok - b * L;
  int t = threadIdx.x;
  int c = t * 4;
  int h = t >> 4;
  int d = c & 63;
  const u16* rowq = qkvb + (size_t)tok * 3072 + c;
  u16x4 qv = *(const u16x4*)rowq;
  u16x4 kv = *(const u16x4*)(rowq + 1024);
  float qf[4], kf[4], ssq = 0.f, ssk = 0.f;
#pragma unroll
  for (int j = 0; j < 4; j++){
    qf[j] = b2f(qv[j]); kf[j] = b2f(kv[j]);
    ssq += qf[j] * qf[j]; ssk += kf[j] * kf[j];
  }
#pragma unroll
  for (int msk = 1; msk < 16; msk <<= 1){
    ssq += __shfl_xor(ssq, msk);
    ssk += __shfl_xor(ssk, msk);
  }
  // 8 (SCALE_RMS) * 0.125 (SCALE_ATTN) * log2(e) = log2(e)
  float sq = 1.44269504088896340736f / fmaxf(sqrtf(ssq), 1e-12f);
  float sk = 8.0f / fmaxf(sqrtf(ssk), 1e-12f);
  u16x4 qo, ko;
#pragma unroll
  for (int j = 0; j < 4; j++){
    qo[j] = f2bf(qf[j] * sq * gq[h * 64 + d + j]);
    ko[j] = f2bf(kf[j] * sk * gk[h * 64 + d + j]);
  }
  *(u16x4*)(qdst + ((size_t)(b * 16 + h) * qL + qoff + l) * 64 + d) = qo;
  *(u16x4*)(kdst + ((size_t)(b * 16 + h) * 3584 + kvoff + l) * 64 + d) = ko;
}

// ---------------- V transpose: qkvb v-part -> vT (B,H,64,3584) ----------------
__global__ __launch_bounds__(256) void vtrans(const u16* __restrict__ qkvb, int L,
                                              u16* __restrict__ vT, int kvoff){
  __shared__ u16 tile[64][65];
  int l0 = blockIdx.x * 64; int h = blockIdx.y; int b = blockIdx.z;
  int t = threadIdx.x;
#pragma unroll
  for (int j = 0; j < 16; j++){
    int idx = j * 256 + t;
    int r = idx >> 6, d = idx & 63;
    tile[r][d] = qkvb[(size_t)(b * L + l0 + r) * 3072 + 2048 + h * 64 + d];
  }
  __syncthreads();
#pragma unroll
  for (int j = 0; j < 16; j++){
    int idx = j * 256 + t;
    int d = idx >> 6, r = idx & 63;
    vT[((size_t)(b * 16 + h) * 64 + d) * 3584 + kvoff + l0 + r] = tile[r][d];
  }
}

// ---------------- flash attention (v5: VALU-cut softmax) ----------------
// v4 + (1) Q pre-scaled (no per-score mul), (2) cvt_pk_bf16 packing (96->16 ops),
// (3) defer-rescale: skip acc*al when the wave's running max didn't grow (~90% of
// tiles), (4) s_setprio(1) around MFMA clusters (T5).
__global__ __launch_bounds__(128, 3) void attn(const u16* __restrict__ q0, const u16* __restrict__ q1,
                                               const u16* __restrict__ kmat, const u16* __restrict__ vTm,
                                               u16* __restrict__ ob0, u16* __restrict__ ob1,
                                               u16* __restrict__ ob2){
  __shared__ __align__(16) u16 smK[64 * 72];      // [key][feat]
  __shared__ __align__(16) u16 smV[64 * 72];      // [d][kv]
  __shared__ __align__(16) u16 smP[2][32 * 68];   // per-wave P [qrow][key]
  int lin = blockIdx.x;
  bool t1 = lin < 768;                 // task1 = joint attn (24 qb x 32 hb)
  int rel = t1 ? lin : lin - 768;
  int qb = rel >> 5, hb = rel & 31;
  int h = hb & 15, b = hb >> 4;
  int bh = b * 16 + h;
  const u16* qp = t1 ? q1 : q0;
  int Lq  = t1 ? 1536 : 2048;
  int kvo = t1 ? 0    : 1536;
  int Lk  = t1 ? 3584 : 2048;
  u16* out0 = t1 ? ob1 : ob0;  int L0 = t1 ? 1024 : 2048;
  u16* out1 = t1 ? ob2 : ob0;  int L1 = t1 ? 512  : 2048;

  int t = threadIdx.x, lane = t & 63, w = t >> 6;
  int li = lane & 15, g = lane >> 4;

  // Q fragments: rows qb*64 + w*32 + qg*16 + li
  const u16* qbase = qp + ((size_t)bh * Lq + qb * 64 + w * 32) * 64;
  bf16x8 qa[2][2];
#pragma unroll
  for (int qg = 0; qg < 2; qg++)
#pragma unroll
    for (int kh = 0; kh < 2; kh++)
      qa[qg][kh] = *(const bf16x8*)(qbase + (size_t)(qg * 16 + li) * 64 + kh * 32 + g * 8);

  // acc[qg][dt] = O^T fragment: lane li = q-row qg*16+li, values d = dt*16 + g*4 + r
  f32x4 acc[2][4] = {};
  float mrunL[2] = {-3.0e38f, -3.0e38f};
  float lsumL[2] = {0.f, 0.f};   // per-lane partial over this lane's 16 keys/tile

  const u16* kbase = kmat + ((size_t)bh * 3584 + kvo) * 64;
  const u16* vbase = vTm + (size_t)bh * 64 * 3584 + kvo;
  u16* pp = &smP[w][0];

  // staging: 64 rows x 8 x 16B = 512 units over 128 threads -> 4 units each (K and V)
  u16x8 ka[4], va[4];
#pragma unroll
  for (int j = 0; j < 4; j++){
    int u = t + j * 128; int ur = u >> 3, us = (u & 7) * 8;
    ka[j] = *(const u16x8*)(kbase + (size_t)ur * 64 + us);
    va[j] = *(const u16x8*)(vbase + (size_t)ur * 3584 + us);
  }

  for (int kt = 0; kt < Lk; kt += 64){
    __syncthreads();   // prior tile fully consumed by both waves
#pragma unroll
    for (int j = 0; j < 4; j++){
      int u = t + j * 128; int ur = u >> 3, us = (u & 7) * 8;
      *(u16x8*)&smK[ur * 72 + us] = ka[j];
      *(u16x8*)&smV[ur * 72 + us] = va[j];
    }
    __syncthreads();
    if (kt + 64 < Lk){   // prefetch next tile (hides HBM/L2 latency under compute)
#pragma unroll
      for (int j = 0; j < 4; j++){
        int u = t + j * 128; int ur = u >> 3, us = (u & 7) * 8;
        ka[j] = *(const u16x8*)(kbase + (size_t)(kt + 64 + ur) * 64 + us);
        va[j] = *(const u16x8*)(vbase + (size_t)ur * 3584 + kt + 64 + us);
      }
    }

    // ---- S^T = K Q^T (scores already in exp2 domain via Q pre-scale) ----
    f32x4 sT[2][4];   // [qg][kg]
    __builtin_amdgcn_s_setprio(1);
#pragma unroll
    for (int kg = 0; kg < 4; kg++){
      bf16x8 kf0 = *(const bf16x8*)&smK[(kg * 16 + li) * 72 + g * 8];
      bf16x8 kf1 = *(const bf16x8*)&smK[(kg * 16 + li) * 72 + 32 + g * 8];
#pragma unroll
      for (int qg = 0; qg < 2; qg++){
        f32x4 z = {};
        z = MFMA(kf0, qa[qg][0], z);
        sT[qg][kg] = MFMA(kf1, qa[qg][1], z);
      }
    }
    __builtin_amdgcn_s_setprio(0);

    // ---- per-row max: register tree + 2 shfl ----
    float rm[2];
#pragma unroll
    for (int qg = 0; qg < 2; qg++){
      float m01 = fmaxf(fmaxf(sT[qg][0][0], sT[qg][0][1]), fmaxf(sT[qg][0][2], sT[qg][0][3]));
      float m23 = fmaxf(fmaxf(sT[qg][1][0], sT[qg][1][1]), fmaxf(sT[qg][1][2], sT[qg][1][3]));
      float m45 = fmaxf(fmaxf(sT[qg][2][0], sT[qg][2][1]), fmaxf(sT[qg][2][2], sT[qg][2][3]));
      float m67 = fmaxf(fmaxf(sT[qg][3][0], sT[qg][3][1]), fmaxf(sT[qg][3][2], sT[qg][3][3]));
      float v = fmaxf(fmaxf(m01, m23), fmaxf(m45, m67));
      v = fmaxf(v, __shfl_xor(v, 16));
      v = fmaxf(v, __shfl_xor(v, 32));
      rm[qg] = v;
    }

    // ---- defer-rescale: only pay al-mult when any row's max grew ----
    if (__any((rm[0] > mrunL[0]) | (rm[1] > mrunL[1]))){
#pragma unroll
      for (int qg = 0; qg < 2; qg++){
        float mo = mrunL[qg];
        float mn = fmaxf(mo, rm[qg]);
        float al = __builtin_exp2f(mo - mn);
        mrunL[qg] = mn;
        lsumL[qg] *= al;
#pragma unroll
        for (int dt = 0; dt < 4; dt++)
#pragma unroll
          for (int r = 0; r < 4; r++) acc[qg][dt][r] *= al;
      }
    }

    // ---- P = exp2(S - m), pack via cvt_pk, store to per-wave LDS ----
#pragma unroll
    for (int qg = 0; qg < 2; qg++){
      float mn = mrunL[qg];
      float ps = 0.f;
#pragma unroll
      for (int kg = 0; kg < 4; kg++){
        float p0 = __builtin_exp2f(sT[qg][kg][0] - mn);
        float p1 = __builtin_exp2f(sT[qg][kg][1] - mn);
        float p2 = __builtin_exp2f(sT[qg][kg][2] - mn);
        float p3 = __builtin_exp2f(sT[qg][kg][3] - mn);
        ps += (p0 + p1) + (p2 + p3);
        u32x2 pk; pk[0] = cvtpk(p0, p1); pk[1] = cvtpk(p2, p3);
        *(u32x2*)&pp[(qg * 16 + li) * 68 + kg * 16 + g * 4] = pk;
      }
      lsumL[qg] += ps;
    }

    // ---- O^T += V^T P^T : acc lane li = q-row li ----
    bf16x8 pf[2][2];
#pragma unroll
    for (int qg = 0; qg < 2; qg++){
      pf[qg][0] = *(const bf16x8*)&pp[(qg * 16 + li) * 68 + g * 8];
      pf[qg][1] = *(const bf16x8*)&pp[(qg * 16 + li) * 68 + 32 + g * 8];
    }
    __builtin_amdgcn_s_setprio(1);
#pragma unroll
    for (int dt = 0; dt < 4; dt++){
      bf16x8 vf0 = *(const bf16x8*)&smV[(dt * 16 + li) * 72 + g * 8];
      bf16x8 vf1 = *(const bf16x8*)&smV[(dt * 16 + li) * 72 + 32 + g * 8];
#pragma unroll
      for (int qg = 0; qg < 2; qg++){
        acc[qg][dt] = MFMA(vf0, pf[qg][0], acc[qg][dt]);
        acc[qg][dt] = MFMA(vf1, pf[qg][1], acc[qg][dt]);
      }
    }
    __builtin_amdgcn_s_setprio(0);
  }

  // ---- epilogue: 2-shfl sum reduce, lane-local normalize, u16x4 stores ----
#pragma unroll
  for (int qg = 0; qg < 2; qg++){
    float ls = lsumL[qg];
    ls += __shfl_xor(ls, 16);
    ls += __shfl_xor(ls, 32);
    float inv = 1.0f / ls;
    int qi = qb * 64 + w * 32 + qg * 16 + li;
    u16* dst; size_t basei;
    if (qi < L0){ dst = out0; basei = ((size_t)(b * L0 + qi)) * 1024 + h * 64; }
    else        { dst = out1; basei = ((size_t)(b * L1 + (qi - L0))) * 1024 + h * 64; }
#pragma unroll
    for (int dt = 0; dt < 4; dt++){
      u16x4 o;
#pragma unroll
      for (int r = 0; r < 4; r++) o[r] = f2bf(acc[qg][dt][r] * inv);
      *(u16x4*)&dst[basei + dt * 16 + g * 4] = o;
    }
  }
}

// ---------------- launch ----------------
extern "C" void kernel_launch(void* const* d_in, const int* in_sizes, int n_in,
                              void* d_out, int out_size, void* d_ws, size_t ws_size,
                              hipStream_t stream){
  (void)in_sizes; (void)n_in; (void)out_size; (void)ws_size;
  const float* x[3]    = {(const float*)d_in[0],  (const float*)d_in[7],  (const float*)d_in[14]};
  const float* Wqkv[3] = {(const float*)d_in[1],  (const float*)d_in[8],  (const float*)d_in[15]};
  const float* bqkv[3] = {(const float*)d_in[2],  (const float*)d_in[9],  (const float*)d_in[16]};
  const float* gq[3]   = {(const float*)d_in[3],  (const float*)d_in[10], (const float*)d_in[17]};
  const float* gk[3]   = {(const float*)d_in[4],  (const float*)d_in[11], (const float*)d_in[18]};
  const float* Wout[3] = {(const float*)d_in[5],  (const float*)d_in[12], (const float*)d_in[19]};
  const float* bout[3] = {(const float*)d_in[6],  (const float*)d_in[13], (const float*)d_in[20]};
  float* outp = (float*)d_out;

  const int Ms[3] = {4096, 2048, 1024};   // B*L per modality
  const int Ls[3] = {2048, 1024, 512};
  const int kvoffs[3] = {1536, 0, 1024};  // joint KV order: [texture, color, shape]

  u16* base = (u16*)d_ws;
  size_t off = 0;
  auto nxt = [&](size_t e){ u16* r = base + off; off += e; return r; };
  u16* xbf[3];  for (int m = 0; m < 3; m++) xbf[m]  = nxt((size_t)Ms[m] * 1024);
  u16* WqT[3];  for (int m = 0; m < 3; m++) WqT[m]  = nxt((size_t)3072 * 1024);
  u16* WoT[3];  for (int m = 0; m < 3; m++) WoT[m]  = nxt((size_t)1024 * 1024);
  u16* qkvb[3]; for (int m = 0; m < 3; m++) qkvb[m] = nxt((size_t)Ms[m] * 3072);
  u16* qA = nxt((size_t)2 * 16 * 2048 * 64);
  u16* qB = nxt((size_t)2 * 16 * 1536 * 64);
  u16* kB = nxt((size_t)2 * 16 * 3584 * 64);
  // aliases (disjoint lifetimes, stream-ordered):
  u16* vT = WqT[0];                        // vT reuses WqT block: WqT dead after QKV GEMMs
  u16* hb[3]; for (int m = 0; m < 3; m++) hb[m] = xbf[m];  // xbf dead after QKV GEMMs

  // 1) conversions
  for (int m = 0; m < 3; m++){
    int n4 = Ms[m] * 1024 / 4;
    cvt_f32_bf16<<<n4 / 256, 256, 0, stream>>>(x[m], xbf[m], n4);
    tcvt<<<dim3(3072 / 64, 1024 / 64), 256, 0, stream>>>(Wqkv[m], WqT[m], 1024, 3072);
    tcvt<<<dim3(1024 / 64, 1024 / 64), 256, 0, stream>>>(Wout[m], WoT[m], 1024, 1024);
  }
  // 2) qkv projections
  for (int m = 0; m < 3; m++)
    gemm_bt<0><<<dim3(3072 / 128, Ms[m] / 128), 256, 0, stream>>>(
        xbf[m], WqT[m], bqkv[m], qkvb[m], Ms[m], 3072, 1024);
  // 3) RMS + scatter q/k ; transpose v
  rms_scatter<<<Ms[0], 256, 0, stream>>>(qkvb[0], Ls[0], gq[0], gk[0], qA, 2048, 0,    kB, 1536);
  rms_scatter<<<Ms[1], 256, 0, stream>>>(qkvb[1], Ls[1], gq[1], gk[1], qB, 1536, 0,    kB, 0);
  rms_scatter<<<Ms[2], 256, 0, stream>>>(qkvb[2], Ls[2], gq[2], gk[2], qB, 1536, 1024, kB, 1024);
  for (int m = 0; m < 3; m++)
    vtrans<<<dim3(Ls[m] / 64, 16, 2), 256, 0, stream>>>(qkvb[m], Ls[m], vT, kvoffs[m]);
  // 4) both attentions, single launch: 768 joint-attn blocks + 1024 self-attn blocks
  attn<<<1792, 128, 0, stream>>>(qA, qB, kB, vT, hb[0], hb[1], hb[2]);
  // 5) output projections
  float* outs[3] = {outp, outp + (size_t)4096 * 1024, outp + (size_t)6144 * 1024};
  for (int m = 0; m < 3; m++)
    gemm_bt<1><<<dim3(1024 / 128, Ms[m] / 128), 256, 0, stream>>>(
        hb[m], WoT[m], bout[m], outs[m], Ms[m], 1024, 1024);
}

// Round 11
// 500.343 us; speedup vs baseline: 1.4334x; 1.0841x over previous
//
#include <hip/hip_runtime.h>
#include <hip/hip_bf16.h>
#include <stdint.h>

typedef unsigned short u16;
typedef unsigned int u32;
typedef __attribute__((ext_vector_type(8))) short bf16x8;   // 8 bf16 (4 VGPRs), per guide §3
typedef __attribute__((ext_vector_type(4))) float f32x4;
typedef __attribute__((ext_vector_type(2))) unsigned int u32x2;
typedef __attribute__((ext_vector_type(4))) unsigned short u16x4;
typedef __attribute__((ext_vector_type(8))) unsigned short u16x8;

#define DEV __device__ __forceinline__

DEV u16 f2bf(float f){ // round-to-nearest-even f32 -> bf16
  unsigned u = __float_as_uint(f);
  return (u16)((u + 0x7FFFu + ((u >> 16) & 1u)) >> 16);
}
DEV float b2f(u16 v){ return __uint_as_float(((unsigned)v) << 16); }

DEV u32 cvtpk(float lo, float hi){  // packed f32x2 -> bf16x2 (RNE), 1 instr (T12)
  u32 r;
  asm("v_cvt_pk_bf16_f32 %0, %1, %2" : "=v"(r) : "v"(lo), "v"(hi));
  return r;
}

DEV f32x4 MFMA(bf16x8 a, bf16x8 b, f32x4 c){
  // D = A*B + C ; a = rows of A (M,K), b = rows of B^T (N,K) -> computes A·B
  return __builtin_amdgcn_mfma_f32_16x16x32_bf16(a, b, c, 0, 0, 0);
}

// async global->LDS, 16B per lane; LDS dest = wave-uniform base + lane*16 (m97/m104)
DEV void gload16(const u16* g, u16* l){
  __builtin_amdgcn_global_load_lds((const __attribute__((address_space(1))) u32*)g,
                                   (__attribute__((address_space(3))) u32*)l, 16, 0, 0);
}

// ---------------- elementwise f32 -> bf16 ----------------
__global__ __launch_bounds__(256) void cvt_f32_bf16(const float* __restrict__ in,
                                                    u16* __restrict__ out, int n4){
  int i = blockIdx.x * 256 + threadIdx.x;
  if (i >= n4) return;
  f32x4 v = ((const f32x4*)in)[i];
  u16x4 o;
  o[0] = f2bf(v[0]); o[1] = f2bf(v[1]); o[2] = f2bf(v[2]); o[3] = f2bf(v[3]);
  ((u16x4*)out)[i] = o;
}

// ---------------- transpose + convert: out[c][r] = bf16(in[r][c]) ----------------
__global__ __launch_bounds__(256) void tcvt(const float* __restrict__ in, u16* __restrict__ out,
                                            int R, int C){
  __shared__ float tile[64][65];
  int c0 = blockIdx.x * 64, r0 = blockIdx.y * 64;
  int t = threadIdx.x;
#pragma unroll
  for (int j = 0; j < 16; j++){
    int idx = j * 256 + t;
    int r = idx >> 6, c = idx & 63;
    tile[r][c] = in[(size_t)(r0 + r) * C + c0 + c];
  }
  __syncthreads();
#pragma unroll
  for (int j = 0; j < 16; j++){
    int idx = j * 256 + t;
    int c = idx >> 6, r = idx & 63;
    out[(size_t)(c0 + c) * R + r0 + r] = f2bf(tile[r][c]);
  }
}

// ---------------- merged GEMM x3: out_m(M_m,N) = A_m(M_m,K)*Bt_m(N,K)^T + bias_m ----
// m97 structure: 128x128 tile, BK=32, 4 waves (2x2), global_load_lds w16 staging into
// linear [128][32] LDS (16 KB total -> 10 blocks/CU). blockIdx.y selects modality seg.
template<int F32OUT>
__global__ __launch_bounds__(256) void gemm3(const u16* __restrict__ A0, const u16* __restrict__ A1,
                                             const u16* __restrict__ A2,
                                             const u16* __restrict__ B0, const u16* __restrict__ B1,
                                             const u16* __restrict__ B2,
                                             const float* __restrict__ bi0, const float* __restrict__ bi1,
                                             const float* __restrict__ bi2,
                                             void* __restrict__ o0, void* __restrict__ o1,
                                             void* __restrict__ o2,
                                             int N, int K, int rb0, int rb1){
  __shared__ __align__(16) u16 smA[128 * 32];
  __shared__ __align__(16) u16 smB[128 * 32];
  int yb = blockIdx.y;
  const u16 *A, *Bt; const float* bias; void* outp;
  int m0;
  if (yb < rb0)            { A = A0; Bt = B0; bias = bi0; outp = o0; m0 = yb * 128; }
  else if (yb < rb0 + rb1) { A = A1; Bt = B1; bias = bi1; outp = o1; m0 = (yb - rb0) * 128; }
  else                     { A = A2; Bt = B2; bias = bi2; outp = o2; m0 = (yb - rb0 - rb1) * 128; }

  int t = threadIdx.x;
  int lane = t & 63, w = t >> 6;
  int wr = w >> 1, wc = w & 1;
  int li = lane & 15, g = lane >> 4;
  int n0 = blockIdx.x * 128;

  // staging: wave w covers rows [w*32, w*32+32) of each tile via 2 calls (16 rows each)
  int srow = w * 32 + (lane >> 2);       // + j*16
  int sk = (lane & 3) * 8;
  const u16* Ag0 = A  + (size_t)(m0 + srow) * K + sk;
  const u16* Ag1 = A  + (size_t)(m0 + srow + 16) * K + sk;
  const u16* Bg0 = Bt + (size_t)(n0 + srow) * K + sk;
  const u16* Bg1 = Bt + (size_t)(n0 + srow + 16) * K + sk;
  u16* la0 = &smA[w * 1024];             // wave-uniform LDS bases
  u16* la1 = &smA[w * 1024 + 512];
  u16* lb0 = &smB[w * 1024];
  u16* lb1 = &smB[w * 1024 + 512];

  f32x4 acc[4][4] = {};

  for (int kt = 0; kt < K; kt += 32){
    __syncthreads();                     // prior tile fully consumed
    gload16(Ag0 + kt, la0);
    gload16(Ag1 + kt, la1);
    gload16(Bg0 + kt, lb0);
    gload16(Bg1 + kt, lb1);
    __syncthreads();                     // drains vmcnt (barrier semantics) - tile ready

    bf16x8 af[4], bfr[4];
#pragma unroll
    for (int mf = 0; mf < 4; mf++)
      af[mf] = *(const bf16x8*)&smA[(wr * 64 + mf * 16 + li) * 32 + g * 8];
#pragma unroll
    for (int nf = 0; nf < 4; nf++)
      bfr[nf] = *(const bf16x8*)&smB[(wc * 64 + nf * 16 + li) * 32 + g * 8];
#pragma unroll
    for (int mf = 0; mf < 4; mf++)
#pragma unroll
      for (int nf = 0; nf < 4; nf++)
        acc[mf][nf] = MFMA(af[mf], bfr[nf], acc[mf][nf]);
  }

#pragma unroll
  for (int mf = 0; mf < 4; mf++){
    int row = m0 + wr * 64 + mf * 16 + g * 4;
#pragma unroll
    for (int nf = 0; nf < 4; nf++){
      int col = n0 + wc * 64 + nf * 16 + li;
      float bs = bias[col];
#pragma unroll
      for (int r = 0; r < 4; r++){
        float v = acc[mf][nf][r] + bs;
        if (F32OUT) ((float*)outp)[(size_t)(row + r) * N + col] = v;
        else        ((u16*)outp)[(size_t)(row + r) * N + col]  = f2bf(v);
      }
    }
  }
}

// ---------------- RMS (q,k) + scatter into attention layouts ----------------
// q is PRE-SCALED by SCALE_RMS*SCALE_ATTN*log2(e) = log2(e): QK^T lands in exp2 domain.
__global__ __launch_bounds__(256) void rms_scatter(const u16* __restrict__ qkvb, int L,
                                                   const float* __restrict__ gq, const float* __restrict__ gk,
                                                   u16* __restrict__ qdst, int qL, int qoff,
                                                   u16* __restrict__ kdst, int kvoff){
  int tok = blockIdx.x;
  int b = tok / L, l = tok - b * L;
  int t = threadIdx.x;
  int c = t * 4;
  int h = t >> 4;
  int d = c & 63;
  const u16* rowq = qkvb + (size_t)tok * 3072 + c;
  u16x4 qv = *(const u16x4*)rowq;
  u16x4 kv = *(const u16x4*)(rowq + 1024);
  float qf[4], kf[4], ssq = 0.f, ssk = 0.f;
#pragma unroll
  for (int j = 0; j < 4; j++){
    qf[j] = b2f(qv[j]); kf[j] = b2f(kv[j]);
    ssq += qf[j] * qf[j]; ssk += kf[j] * kf[j];
  }
#pragma unroll
  for (int msk = 1; msk < 16; msk <<= 1){
    ssq += __shfl_xor(ssq, msk);
    ssk += __shfl_xor(ssk, msk);
  }
  // 8 (SCALE_RMS) * 0.125 (SCALE_ATTN) * log2(e) = log2(e)
  float sq = 1.44269504088896340736f / fmaxf(sqrtf(ssq), 1e-12f);
  float sk = 8.0f / fmaxf(sqrtf(ssk), 1e-12f);
  u16x4 qo, ko;
#pragma unroll
  for (int j = 0; j < 4; j++){
    qo[j] = f2bf(qf[j] * sq * gq[h * 64 + d + j]);
    ko[j] = f2bf(kf[j] * sk * gk[h * 64 + d + j]);
  }
  *(u16x4*)(qdst + ((size_t)(b * 16 + h) * qL + qoff + l) * 64 + d) = qo;
  *(u16x4*)(kdst + ((size_t)(b * 16 + h) * 3584 + kvoff + l) * 64 + d) = ko;
}

// ---------------- V transpose: qkvb v-part -> vT (B,H,64,3584) ----------------
__global__ __launch_bounds__(256) void vtrans(const u16* __restrict__ qkvb, int L,
                                              u16* __restrict__ vT, int kvoff){
  __shared__ u16 tile[64][65];
  int l0 = blockIdx.x * 64; int h = blockIdx.y; int b = blockIdx.z;
  int t = threadIdx.x;
#pragma unroll
  for (int j = 0; j < 16; j++){
    int idx = j * 256 + t;
    int r = idx >> 6, d = idx & 63;
    tile[r][d] = qkvb[(size_t)(b * L + l0 + r) * 3072 + 2048 + h * 64 + d];
  }
  __syncthreads();
#pragma unroll
  for (int j = 0; j < 16; j++){
    int idx = j * 256 + t;
    int d = idx >> 6, r = idx & 63;
    vT[((size_t)(b * 16 + h) * 64 + d) * 3584 + kvoff + l0 + r] = tile[r][d];
  }
}

// ---------------- flash attention (v5: VALU-cut softmax) ----------------
// swapped QK^T (S^T=K*Q^T, lane-local softmax) + Q pre-scale + cvt_pk packing +
// defer-rescale + setprio. 2 waves x 32 q-rows; KVBLK=64; merged tasks.
__global__ __launch_bounds__(128, 3) void attn(const u16* __restrict__ q0, const u16* __restrict__ q1,
                                               const u16* __restrict__ kmat, const u16* __restrict__ vTm,
                                               u16* __restrict__ ob0, u16* __restrict__ ob1,
                                               u16* __restrict__ ob2){
  __shared__ __align__(16) u16 smK[64 * 72];      // [key][feat]
  __shared__ __align__(16) u16 smV[64 * 72];      // [d][kv]
  __shared__ __align__(16) u16 smP[2][32 * 68];   // per-wave P [qrow][key]
  int lin = blockIdx.x;
  bool t1 = lin < 768;                 // task1 = joint attn (24 qb x 32 hb)
  int rel = t1 ? lin : lin - 768;
  int qb = rel >> 5, hb = rel & 31;
  int h = hb & 15, b = hb >> 4;
  int bh = b * 16 + h;
  const u16* qp = t1 ? q1 : q0;
  int Lq  = t1 ? 1536 : 2048;
  int kvo = t1 ? 0    : 1536;
  int Lk  = t1 ? 3584 : 2048;
  u16* out0 = t1 ? ob1 : ob0;  int L0 = t1 ? 1024 : 2048;
  u16* out1 = t1 ? ob2 : ob0;  int L1 = t1 ? 512  : 2048;

  int t = threadIdx.x, lane = t & 63, w = t >> 6;
  int li = lane & 15, g = lane >> 4;

  // Q fragments: rows qb*64 + w*32 + qg*16 + li
  const u16* qbase = qp + ((size_t)bh * Lq + qb * 64 + w * 32) * 64;
  bf16x8 qa[2][2];
#pragma unroll
  for (int qg = 0; qg < 2; qg++)
#pragma unroll
    for (int kh = 0; kh < 2; kh++)
      qa[qg][kh] = *(const bf16x8*)(qbase + (size_t)(qg * 16 + li) * 64 + kh * 32 + g * 8);

  // acc[qg][dt] = O^T fragment: lane li = q-row qg*16+li, values d = dt*16 + g*4 + r
  f32x4 acc[2][4] = {};
  float mrunL[2] = {-3.0e38f, -3.0e38f};
  float lsumL[2] = {0.f, 0.f};   // per-lane partial over this lane's 16 keys/tile

  const u16* kbase = kmat + ((size_t)bh * 3584 + kvo) * 64;
  const u16* vbase = vTm + (size_t)bh * 64 * 3584 + kvo;
  u16* pp = &smP[w][0];

  // staging: 64 rows x 8 x 16B = 512 units over 128 threads -> 4 units each (K and V)
  u16x8 ka[4], va[4];
#pragma unroll
  for (int j = 0; j < 4; j++){
    int u = t + j * 128; int ur = u >> 3, us = (u & 7) * 8;
    ka[j] = *(const u16x8*)(kbase + (size_t)ur * 64 + us);
    va[j] = *(const u16x8*)(vbase + (size_t)ur * 3584 + us);
  }

  for (int kt = 0; kt < Lk; kt += 64){
    __syncthreads();   // prior tile fully consumed by both waves
#pragma unroll
    for (int j = 0; j < 4; j++){
      int u = t + j * 128; int ur = u >> 3, us = (u & 7) * 8;
      *(u16x8*)&smK[ur * 72 + us] = ka[j];
      *(u16x8*)&smV[ur * 72 + us] = va[j];
    }
    __syncthreads();
    if (kt + 64 < Lk){   // prefetch next tile (hides HBM/L2 latency under compute)
#pragma unroll
      for (int j = 0; j < 4; j++){
        int u = t + j * 128; int ur = u >> 3, us = (u & 7) * 8;
        ka[j] = *(const u16x8*)(kbase + (size_t)(kt + 64 + ur) * 64 + us);
        va[j] = *(const u16x8*)(vbase + (size_t)ur * 3584 + kt + 64 + us);
      }
    }

    // ---- S^T = K Q^T (scores already in exp2 domain via Q pre-scale) ----
    f32x4 sT[2][4];   // [qg][kg]
    __builtin_amdgcn_s_setprio(1);
#pragma unroll
    for (int kg = 0; kg < 4; kg++){
      bf16x8 kf0 = *(const bf16x8*)&smK[(kg * 16 + li) * 72 + g * 8];
      bf16x8 kf1 = *(const bf16x8*)&smK[(kg * 16 + li) * 72 + 32 + g * 8];
#pragma unroll
      for (int qg = 0; qg < 2; qg++){
        f32x4 z = {};
        z = MFMA(kf0, qa[qg][0], z);
        sT[qg][kg] = MFMA(kf1, qa[qg][1], z);
      }
    }
    __builtin_amdgcn_s_setprio(0);

    // ---- per-row max: register tree + 2 shfl ----
    float rm[2];
#pragma unroll
    for (int qg = 0; qg < 2; qg++){
      float m01 = fmaxf(fmaxf(sT[qg][0][0], sT[qg][0][1]), fmaxf(sT[qg][0][2], sT[qg][0][3]));
      float m23 = fmaxf(fmaxf(sT[qg][1][0], sT[qg][1][1]), fmaxf(sT[qg][1][2], sT[qg][1][3]));
      float m45 = fmaxf(fmaxf(sT[qg][2][0], sT[qg][2][1]), fmaxf(sT[qg][2][2], sT[qg][2][3]));
      float m67 = fmaxf(fmaxf(sT[qg][3][0], sT[qg][3][1]), fmaxf(sT[qg][3][2], sT[qg][3][3]));
      float v = fmaxf(fmaxf(m01, m23), fmaxf(m45, m67));
      v = fmaxf(v, __shfl_xor(v, 16));
      v = fmaxf(v, __shfl_xor(v, 32));
      rm[qg] = v;
    }

    // ---- defer-rescale: only pay al-mult when any row's max grew ----
    if (__any((rm[0] > mrunL[0]) | (rm[1] > mrunL[1]))){
#pragma unroll
      for (int qg = 0; qg < 2; qg++){
        float mo = mrunL[qg];
        float mn = fmaxf(mo, rm[qg]);
        float al = __builtin_exp2f(mo - mn);
        mrunL[qg] = mn;
        lsumL[qg] *= al;
#pragma unroll
        for (int dt = 0; dt < 4; dt++)
#pragma unroll
          for (int r = 0; r < 4; r++) acc[qg][dt][r] *= al;
      }
    }

    // ---- P = exp2(S - m), pack via cvt_pk, store to per-wave LDS ----
#pragma unroll
    for (int qg = 0; qg < 2; qg++){
      float mn = mrunL[qg];
      float ps = 0.f;
#pragma unroll
      for (int kg = 0; kg < 4; kg++){
        float p0 = __builtin_exp2f(sT[qg][kg][0] - mn);
        float p1 = __builtin_exp2f(sT[qg][kg][1] - mn);
        float p2 = __builtin_exp2f(sT[qg][kg][2] - mn);
        float p3 = __builtin_exp2f(sT[qg][kg][3] - mn);
        ps += (p0 + p1) + (p2 + p3);
        u32x2 pk; pk[0] = cvtpk(p0, p1); pk[1] = cvtpk(p2, p3);
        *(u32x2*)&pp[(qg * 16 + li) * 68 + kg * 16 + g * 4] = pk;
      }
      lsumL[qg] += ps;
    }

    // ---- O^T += V^T P^T : acc lane li = q-row li ----
    bf16x8 pf[2][2];
#pragma unroll
    for (int qg = 0; qg < 2; qg++){
      pf[qg][0] = *(const bf16x8*)&pp[(qg * 16 + li) * 68 + g * 8];
      pf[qg][1] = *(const bf16x8*)&pp[(qg * 16 + li) * 68 + 32 + g * 8];
    }
    __builtin_amdgcn_s_setprio(1);
#pragma unroll
    for (int dt = 0; dt < 4; dt++){
      bf16x8 vf0 = *(const bf16x8*)&smV[(dt * 16 + li) * 72 + g * 8];
      bf16x8 vf1 = *(const bf16x8*)&smV[(dt * 16 + li) * 72 + 32 + g * 8];
#pragma unroll
      for (int qg = 0; qg < 2; qg++){
        acc[qg][dt] = MFMA(vf0, pf[qg][0], acc[qg][dt]);
        acc[qg][dt] = MFMA(vf1, pf[qg][1], acc[qg][dt]);
      }
    }
    __builtin_amdgcn_s_setprio(0);
  }

  // ---- epilogue: 2-shfl sum reduce, lane-local normalize, u16x4 stores ----
#pragma unroll
  for (int qg = 0; qg < 2; qg++){
    float ls = lsumL[qg];
    ls += __shfl_xor(ls, 16);
    ls += __shfl_xor(ls, 32);
    float inv = 1.0f / ls;
    int qi = qb * 64 + w * 32 + qg * 16 + li;
    u16* dst; size_t basei;
    if (qi < L0){ dst = out0; basei = ((size_t)(b * L0 + qi)) * 1024 + h * 64; }
    else        { dst = out1; basei = ((size_t)(b * L1 + (qi - L0))) * 1024 + h * 64; }
#pragma unroll
    for (int dt = 0; dt < 4; dt++){
      u16x4 o;
#pragma unroll
      for (int r = 0; r < 4; r++) o[r] = f2bf(acc[qg][dt][r] * inv);
      *(u16x4*)&dst[basei + dt * 16 + g * 4] = o;
    }
  }
}

// ---------------- launch ----------------
extern "C" void kernel_launch(void* const* d_in, const int* in_sizes, int n_in,
                              void* d_out, int out_size, void* d_ws, size_t ws_size,
                              hipStream_t stream){
  (void)in_sizes; (void)n_in; (void)out_size; (void)ws_size;
  const float* x[3]    = {(const float*)d_in[0],  (const float*)d_in[7],  (const float*)d_in[14]};
  const float* Wqkv[3] = {(const float*)d_in[1],  (const float*)d_in[8],  (const float*)d_in[15]};
  const float* bqkv[3] = {(const float*)d_in[2],  (const float*)d_in[9],  (const float*)d_in[16]};
  const float* gq[3]   = {(const float*)d_in[3],  (const float*)d_in[10], (const float*)d_in[17]};
  const float* gk[3]   = {(const float*)d_in[4],  (const float*)d_in[11], (const float*)d_in[18]};
  const float* Wout[3] = {(const float*)d_in[5],  (const float*)d_in[12], (const float*)d_in[19]};
  const float* bout[3] = {(const float*)d_in[6],  (const float*)d_in[13], (const float*)d_in[20]};
  float* outp = (float*)d_out;

  const int Ms[3] = {4096, 2048, 1024};   // B*L per modality
  const int Ls[3] = {2048, 1024, 512};
  const int kvoffs[3] = {1536, 0, 1024};  // joint KV order: [texture, color, shape]

  u16* base = (u16*)d_ws;
  size_t off = 0;
  auto nxt = [&](size_t e){ u16* r = base + off; off += e; return r; };
  u16* xbf[3];  for (int m = 0; m < 3; m++) xbf[m]  = nxt((size_t)Ms[m] * 1024);
  u16* WqT[3];  for (int m = 0; m < 3; m++) WqT[m]  = nxt((size_t)3072 * 1024);
  u16* WoT[3];  for (int m = 0; m < 3; m++) WoT[m]  = nxt((size_t)1024 * 1024);
  u16* qkvb[3]; for (int m = 0; m < 3; m++) qkvb[m] = nxt((size_t)Ms[m] * 3072);
  u16* qA = nxt((size_t)2 * 16 * 2048 * 64);
  u16* qB = nxt((size_t)2 * 16 * 1536 * 64);
  u16* kB = nxt((size_t)2 * 16 * 3584 * 64);
  // aliases (disjoint lifetimes, stream-ordered):
  u16* vT = WqT[0];                        // vT reuses WqT block: WqT dead after QKV GEMMs
  u16* hb[3]; for (int m = 0; m < 3; m++) hb[m] = xbf[m];  // xbf dead after QKV GEMMs

  // 1) conversions
  for (int m = 0; m < 3; m++){
    int n4 = Ms[m] * 1024 / 4;
    cvt_f32_bf16<<<n4 / 256, 256, 0, stream>>>(x[m], xbf[m], n4);
    tcvt<<<dim3(3072 / 64, 1024 / 64), 256, 0, stream>>>(Wqkv[m], WqT[m], 1024, 3072);
    tcvt<<<dim3(1024 / 64, 1024 / 64), 256, 0, stream>>>(Wout[m], WoT[m], 1024, 1024);
  }
  // 2) qkv projections - ONE merged dispatch (grid 24 x 56)
  gemm3<0><<<dim3(3072 / 128, 56), 256, 0, stream>>>(
      xbf[0], xbf[1], xbf[2], WqT[0], WqT[1], WqT[2],
      bqkv[0], bqkv[1], bqkv[2], qkvb[0], qkvb[1], qkvb[2],
      3072, 1024, 32, 16);
  // 3) RMS + scatter q/k ; transpose v
  rms_scatter<<<Ms[0], 256, 0, stream>>>(qkvb[0], Ls[0], gq[0], gk[0], qA, 2048, 0,    kB, 1536);
  rms_scatter<<<Ms[1], 256, 0, stream>>>(qkvb[1], Ls[1], gq[1], gk[1], qB, 1536, 0,    kB, 0);
  rms_scatter<<<Ms[2], 256, 0, stream>>>(qkvb[2], Ls[2], gq[2], gk[2], qB, 1536, 1024, kB, 1024);
  for (int m = 0; m < 3; m++)
    vtrans<<<dim3(Ls[m] / 64, 16, 2), 256, 0, stream>>>(qkvb[m], Ls[m], vT, kvoffs[m]);
  // 4) both attentions, single launch: 768 joint-attn blocks + 1024 self-attn blocks
  attn<<<1792, 128, 0, stream>>>(qA, qB, kB, vT, hb[0], hb[1], hb[2]);
  // 5) output projections - ONE merged dispatch (grid 8 x 56)
  float* outs[3] = {outp, outp + (size_t)4096 * 1024, outp + (size_t)6144 * 1024};
  gemm3<1><<<dim3(1024 / 128, 56), 256, 0, stream>>>(
      hb[0], hb[1], hb[2], WoT[0], WoT[1], WoT[2],
      bout[0], bout[1], bout[2], outs[0], outs[1], outs[2],
      1024, 1024, 32, 16);
}

// Round 12
// 471.447 us; speedup vs baseline: 1.5212x; 1.0613x over previous
//
#include <hip/hip_runtime.h>
#include <hip/hip_bf16.h>
#include <stdint.h>

typedef unsigned short u16;
typedef unsigned int u32;
typedef __attribute__((ext_vector_type(8))) short bf16x8;   // 8 bf16 (4 VGPRs), per guide §3
typedef __attribute__((ext_vector_type(4))) float f32x4;
typedef __attribute__((ext_vector_type(2))) unsigned int u32x2;
typedef __attribute__((ext_vector_type(4))) unsigned short u16x4;
typedef __attribute__((ext_vector_type(8))) unsigned short u16x8;

#define DEV __device__ __forceinline__

DEV u16 f2bf(float f){ // round-to-nearest-even f32 -> bf16
  unsigned u = __float_as_uint(f);
  return (u16)((u + 0x7FFFu + ((u >> 16) & 1u)) >> 16);
}
DEV float b2f(u16 v){ return __uint_as_float(((unsigned)v) << 16); }

DEV u32 cvtpk(float lo, float hi){  // packed f32x2 -> bf16x2 (RNE), 1 instr (T12)
  u32 r;
  asm("v_cvt_pk_bf16_f32 %0, %1, %2" : "=v"(r) : "v"(lo), "v"(hi));
  return r;
}

DEV f32x4 MFMA(bf16x8 a, bf16x8 b, f32x4 c){
  // D = A*B + C ; a = rows of A (M,K), b = rows of B^T (N,K) -> computes A·B
  return __builtin_amdgcn_mfma_f32_16x16x32_bf16(a, b, c, 0, 0, 0);
}

// async global->LDS, 16B per lane; LDS dest = wave-uniform base + lane*16 (m97/m104)
DEV void gload16(const u16* g, u16* l){
  __builtin_amdgcn_global_load_lds((const __attribute__((address_space(1))) u32*)g,
                                   (__attribute__((address_space(3))) u32*)l, 16, 0, 0);
}

// ---------------- merged f32 -> bf16 (all 3 x tensors, 1 dispatch) ----------------
// out = contiguous xbf area (xbf[0..2] allocated back-to-back in ws)
__global__ __launch_bounds__(256) void cvt3(const float* __restrict__ x0, const float* __restrict__ x1,
                                            const float* __restrict__ x2, u16* __restrict__ out){
  int i = blockIdx.x * 256 + threadIdx.x;     // u16x4 units; total 1,835,008
  const float* src; int base;
  if (i < 1048576)      { src = x0; base = 0; }
  else if (i < 1572864) { src = x1; base = 1048576; }
  else                  { src = x2; base = 1572864; }
  f32x4 v = ((const f32x4*)src)[i - base];
  u16x4 o;
  o[0] = f2bf(v[0]); o[1] = f2bf(v[1]); o[2] = f2bf(v[2]); o[3] = f2bf(v[3]);
  ((u16x4*)out)[i] = o;
}

// ---------------- merged transpose+convert (all 6 W matrices, 1 dispatch) ----------
// out[c][r] = bf16(in[r][c]); R=1024 for all; C=3072 (Wqkv) or 1024 (Wout).
__global__ __launch_bounds__(256) void tcvt6(const float* __restrict__ q0, const float* __restrict__ q1,
                                             const float* __restrict__ q2,
                                             const float* __restrict__ o0, const float* __restrict__ o1,
                                             const float* __restrict__ o2,
                                             u16* __restrict__ Q0, u16* __restrict__ Q1, u16* __restrict__ Q2,
                                             u16* __restrict__ O0, u16* __restrict__ O1, u16* __restrict__ O2){
  __shared__ float tile[64][65];
  int lin = blockIdx.x;                        // [0, 3072): 3x768 Wqkv tiles + 3x256 Wout
  const float* in; u16* out; int C, u;
  if (lin < 2304){
    int s = lin / 768; u = lin - s * 768;
    in = s == 0 ? q0 : (s == 1 ? q1 : q2);
    out = s == 0 ? Q0 : (s == 1 ? Q1 : Q2);
    C = 3072;
  } else {
    int s = (lin - 2304) / 256; u = (lin - 2304) - s * 256;
    in = s == 0 ? o0 : (s == 1 ? o1 : o2);
    out = s == 0 ? O0 : (s == 1 ? O1 : O2);
    C = 1024;
  }
  int ct = C >> 6;
  int c0 = (u % ct) * 64, r0 = (u / ct) * 64;
  const int R = 1024;
  int t = threadIdx.x;
#pragma unroll
  for (int j = 0; j < 16; j++){
    int idx = j * 256 + t;
    int r = idx >> 6, c = idx & 63;
    tile[r][c] = in[(size_t)(r0 + r) * C + c0 + c];
  }
  __syncthreads();
#pragma unroll
  for (int j = 0; j < 16; j++){
    int idx = j * 256 + t;
    int c = idx >> 6, r = idx & 63;
    out[(size_t)(c0 + c) * R + r0 + r] = f2bf(tile[r][c]);
  }
}

// ---------------- merged GEMM x3 with 2-phase pipeline (T3 minimum recipe) ----------
// 128x128 tile, BK=32, 4 waves (2x2), global_load_lds w16 into double-buffered LDS
// (2x16KB -> 5 blocks/CU). ONE barrier per K-step; next-tile STAGE issued before the
// current tile's ds_read+MFMA so HBM latency hides under compute.
template<int F32OUT>
__global__ __launch_bounds__(256) void gemm3(const u16* __restrict__ A0, const u16* __restrict__ A1,
                                             const u16* __restrict__ A2,
                                             const u16* __restrict__ B0, const u16* __restrict__ B1,
                                             const u16* __restrict__ B2,
                                             const float* __restrict__ bi0, const float* __restrict__ bi1,
                                             const float* __restrict__ bi2,
                                             void* __restrict__ o0, void* __restrict__ o1,
                                             void* __restrict__ o2,
                                             int N, int K, int rb0, int rb1){
  __shared__ __align__(16) u16 smA[2][128 * 32];
  __shared__ __align__(16) u16 smB[2][128 * 32];
  int yb = blockIdx.y;
  const u16 *A, *Bt; const float* bias; void* outp;
  int m0;
  if (yb < rb0)            { A = A0; Bt = B0; bias = bi0; outp = o0; m0 = yb * 128; }
  else if (yb < rb0 + rb1) { A = A1; Bt = B1; bias = bi1; outp = o1; m0 = (yb - rb0) * 128; }
  else                     { A = A2; Bt = B2; bias = bi2; outp = o2; m0 = (yb - rb0 - rb1) * 128; }

  int t = threadIdx.x;
  int lane = t & 63, w = t >> 6;
  int wr = w >> 1, wc = w & 1;
  int li = lane & 15, g = lane >> 4;
  int n0 = blockIdx.x * 128;

  // staging: wave w covers rows [w*32, w*32+32) of each tile via 2 calls (16 rows each)
  int srow = w * 32 + (lane >> 2);       // + j*16
  int sk = (lane & 3) * 8;
  const u16* Ag0 = A  + (size_t)(m0 + srow) * K + sk;
  const u16* Ag1 = A  + (size_t)(m0 + srow + 16) * K + sk;
  const u16* Bg0 = Bt + (size_t)(n0 + srow) * K + sk;
  const u16* Bg1 = Bt + (size_t)(n0 + srow + 16) * K + sk;
  int wb = w * 1024;

  // prologue: stage tile 0 into buf 0
  gload16(Ag0, &smA[0][wb]);
  gload16(Ag1, &smA[0][wb + 512]);
  gload16(Bg0, &smB[0][wb]);
  gload16(Bg1, &smB[0][wb + 512]);

  f32x4 acc[4][4] = {};
  int cur = 0;
  for (int kt = 0; kt < K; kt += 32){
    __syncthreads();                     // drains stage into cur (vmcnt at barrier);
                                         // protects buf cur^1 against iter-1 readers
    if (kt + 32 < K){
      int nx = cur ^ 1;                  // issue next-tile loads BEFORE compute
      gload16(Ag0 + kt + 32, &smA[nx][wb]);
      gload16(Ag1 + kt + 32, &smA[nx][wb + 512]);
      gload16(Bg0 + kt + 32, &smB[nx][wb]);
      gload16(Bg1 + kt + 32, &smB[nx][wb + 512]);
    }
    bf16x8 af[4], bfr[4];
#pragma unroll
    for (int mf = 0; mf < 4; mf++)
      af[mf] = *(const bf16x8*)&smA[cur][(wr * 64 + mf * 16 + li) * 32 + g * 8];
#pragma unroll
    for (int nf = 0; nf < 4; nf++)
      bfr[nf] = *(const bf16x8*)&smB[cur][(wc * 64 + nf * 16 + li) * 32 + g * 8];
#pragma unroll
    for (int mf = 0; mf < 4; mf++)
#pragma unroll
      for (int nf = 0; nf < 4; nf++)
        acc[mf][nf] = MFMA(af[mf], bfr[nf], acc[mf][nf]);
    cur ^= 1;
  }

#pragma unroll
  for (int mf = 0; mf < 4; mf++){
    int row = m0 + wr * 64 + mf * 16 + g * 4;
#pragma unroll
    for (int nf = 0; nf < 4; nf++){
      int col = n0 + wc * 64 + nf * 16 + li;
      float bs = bias[col];
#pragma unroll
      for (int r = 0; r < 4; r++){
        float v = acc[mf][nf][r] + bs;
        if (F32OUT) ((float*)outp)[(size_t)(row + r) * N + col] = v;
        else        ((u16*)outp)[(size_t)(row + r) * N + col]  = f2bf(v);
      }
    }
  }
}

// ---------------- merged RMS (q,k) + scatter, all 3 modalities (1 dispatch) --------
// q is PRE-SCALED by SCALE_RMS*SCALE_ATTN*log2(e) = log2(e): QK^T lands in exp2 domain.
__global__ __launch_bounds__(256) void rms3(const u16* __restrict__ qkvb0, const u16* __restrict__ qkvb1,
                                            const u16* __restrict__ qkvb2,
                                            const float* __restrict__ gq0, const float* __restrict__ gk0,
                                            const float* __restrict__ gq1, const float* __restrict__ gk1,
                                            const float* __restrict__ gq2, const float* __restrict__ gk2,
                                            u16* __restrict__ qA, u16* __restrict__ qB,
                                            u16* __restrict__ kB){
  int tok = blockIdx.x;                        // [0, 7168)
  const u16* qkvb; const float *gq, *gk; u16* qdst;
  int L, qL, qoff, kvoff, rel;
  if (tok < 4096)      { rel = tok;        qkvb = qkvb0; gq = gq0; gk = gk0; qdst = qA; L = 2048; qL = 2048; qoff = 0;    kvoff = 1536; }
  else if (tok < 6144) { rel = tok - 4096; qkvb = qkvb1; gq = gq1; gk = gk1; qdst = qB; L = 1024; qL = 1536; qoff = 0;    kvoff = 0; }
  else                 { rel = tok - 6144; qkvb = qkvb2; gq = gq2; gk = gk2; qdst = qB; L = 512;  qL = 1536; qoff = 1024; kvoff = 1024; }
  int b = rel / L, l = rel - b * L;
  int t = threadIdx.x;
  int c = t * 4;
  int h = t >> 4;
  int d = c & 63;
  const u16* rowq = qkvb + (size_t)rel * 3072 + c;
  u16x4 qv = *(const u16x4*)rowq;
  u16x4 kv = *(const u16x4*)(rowq + 1024);
  float qf[4], kf[4], ssq = 0.f, ssk = 0.f;
#pragma unroll
  for (int j = 0; j < 4; j++){
    qf[j] = b2f(qv[j]); kf[j] = b2f(kv[j]);
    ssq += qf[j] * qf[j]; ssk += kf[j] * kf[j];
  }
#pragma unroll
  for (int msk = 1; msk < 16; msk <<= 1){
    ssq += __shfl_xor(ssq, msk);
    ssk += __shfl_xor(ssk, msk);
  }
  // 8 (SCALE_RMS) * 0.125 (SCALE_ATTN) * log2(e) = log2(e)
  float sq = 1.44269504088896340736f / fmaxf(sqrtf(ssq), 1e-12f);
  float sk = 8.0f / fmaxf(sqrtf(ssk), 1e-12f);
  u16x4 qo, ko;
#pragma unroll
  for (int j = 0; j < 4; j++){
    qo[j] = f2bf(qf[j] * sq * gq[h * 64 + d + j]);
    ko[j] = f2bf(kf[j] * sk * gk[h * 64 + d + j]);
  }
  *(u16x4*)(qdst + ((size_t)(b * 16 + h) * qL + qoff + l) * 64 + d) = qo;
  *(u16x4*)(kB + ((size_t)(b * 16 + h) * 3584 + kvoff + l) * 64 + d) = ko;
}

// ---------------- merged V transpose, all 3 modalities (1 dispatch) ----------------
__global__ __launch_bounds__(256) void vtrans3(const u16* __restrict__ qkvb0, const u16* __restrict__ qkvb1,
                                               const u16* __restrict__ qkvb2, u16* __restrict__ vT){
  __shared__ u16 tile[64][65];
  int lt = blockIdx.x;                         // [0,56): 32 shape + 16 texture + 8 color
  int h = blockIdx.y, b = blockIdx.z;
  const u16* qkvb; int L, l0, kvoff;
  if (lt < 32)      { qkvb = qkvb0; L = 2048; l0 = lt * 64;        kvoff = 1536; }
  else if (lt < 48) { qkvb = qkvb1; L = 1024; l0 = (lt - 32) * 64; kvoff = 0; }
  else              { qkvb = qkvb2; L = 512;  l0 = (lt - 48) * 64; kvoff = 1024; }
  int t = threadIdx.x;
#pragma unroll
  for (int j = 0; j < 16; j++){
    int idx = j * 256 + t;
    int r = idx >> 6, d = idx & 63;
    tile[r][d] = qkvb[(size_t)(b * L + l0 + r) * 3072 + 2048 + h * 64 + d];
  }
  __syncthreads();
#pragma unroll
  for (int j = 0; j < 16; j++){
    int idx = j * 256 + t;
    int d = idx >> 6, r = idx & 63;
    vT[((size_t)(b * 16 + h) * 64 + d) * 3584 + kvoff + l0 + r] = tile[r][d];
  }
}

// ---------------- flash attention (v5: VALU-cut softmax) ----------------
// swapped QK^T (S^T=K*Q^T, lane-local softmax) + Q pre-scale + cvt_pk packing +
// defer-rescale + setprio. 2 waves x 32 q-rows; KVBLK=64; merged tasks.
__global__ __launch_bounds__(128, 3) void attn(const u16* __restrict__ q0, const u16* __restrict__ q1,
                                               const u16* __restrict__ kmat, const u16* __restrict__ vTm,
                                               u16* __restrict__ ob0, u16* __restrict__ ob1,
                                               u16* __restrict__ ob2){
  __shared__ __align__(16) u16 smK[64 * 72];      // [key][feat]
  __shared__ __align__(16) u16 smV[64 * 72];      // [d][kv]
  __shared__ __align__(16) u16 smP[2][32 * 68];   // per-wave P [qrow][key]
  int lin = blockIdx.x;
  bool t1 = lin < 768;                 // task1 = joint attn (24 qb x 32 hb)
  int rel = t1 ? lin : lin - 768;
  int qb = rel >> 5, hb = rel & 31;
  int h = hb & 15, b = hb >> 4;
  int bh = b * 16 + h;
  const u16* qp = t1 ? q1 : q0;
  int Lq  = t1 ? 1536 : 2048;
  int kvo = t1 ? 0    : 1536;
  int Lk  = t1 ? 3584 : 2048;
  u16* out0 = t1 ? ob1 : ob0;  int L0 = t1 ? 1024 : 2048;
  u16* out1 = t1 ? ob2 : ob0;  int L1 = t1 ? 512  : 2048;

  int t = threadIdx.x, lane = t & 63, w = t >> 6;
  int li = lane & 15, g = lane >> 4;

  // Q fragments: rows qb*64 + w*32 + qg*16 + li
  const u16* qbase = qp + ((size_t)bh * Lq + qb * 64 + w * 32) * 64;
  bf16x8 qa[2][2];
#pragma unroll
  for (int qg = 0; qg < 2; qg++)
#pragma unroll
    for (int kh = 0; kh < 2; kh++)
      qa[qg][kh] = *(const bf16x8*)(qbase + (size_t)(qg * 16 + li) * 64 + kh * 32 + g * 8);

  // acc[qg][dt] = O^T fragment: lane li = q-row qg*16+li, values d = dt*16 + g*4 + r
  f32x4 acc[2][4] = {};
  float mrunL[2] = {-3.0e38f, -3.0e38f};
  float lsumL[2] = {0.f, 0.f};   // per-lane partial over this lane's 16 keys/tile

  const u16* kbase = kmat + ((size_t)bh * 3584 + kvo) * 64;
  const u16* vbase = vTm + (size_t)bh * 64 * 3584 + kvo;
  u16* pp = &smP[w][0];

  // staging: 64 rows x 8 x 16B = 512 units over 128 threads -> 4 units each (K and V)
  u16x8 ka[4], va[4];
#pragma unroll
  for (int j = 0; j < 4; j++){
    int u = t + j * 128; int ur = u >> 3, us = (u & 7) * 8;
    ka[j] = *(const u16x8*)(kbase + (size_t)ur * 64 + us);
    va[j] = *(const u16x8*)(vbase + (size_t)ur * 3584 + us);
  }

  for (int kt = 0; kt < Lk; kt += 64){
    __syncthreads();   // prior tile fully consumed by both waves
#pragma unroll
    for (int j = 0; j < 4; j++){
      int u = t + j * 128; int ur = u >> 3, us = (u & 7) * 8;
      *(u16x8*)&smK[ur * 72 + us] = ka[j];
      *(u16x8*)&smV[ur * 72 + us] = va[j];
    }
    __syncthreads();
    if (kt + 64 < Lk){   // prefetch next tile (hides HBM/L2 latency under compute)
#pragma unroll
      for (int j = 0; j < 4; j++){
        int u = t + j * 128; int ur = u >> 3, us = (u & 7) * 8;
        ka[j] = *(const u16x8*)(kbase + (size_t)(kt + 64 + ur) * 64 + us);
        va[j] = *(const u16x8*)(vbase + (size_t)ur * 3584 + kt + 64 + us);
      }
    }

    // ---- S^T = K Q^T (scores already in exp2 domain via Q pre-scale) ----
    f32x4 sT[2][4];   // [qg][kg]
    __builtin_amdgcn_s_setprio(1);
#pragma unroll
    for (int kg = 0; kg < 4; kg++){
      bf16x8 kf0 = *(const bf16x8*)&smK[(kg * 16 + li) * 72 + g * 8];
      bf16x8 kf1 = *(const bf16x8*)&smK[(kg * 16 + li) * 72 + 32 + g * 8];
#pragma unroll
      for (int qg = 0; qg < 2; qg++){
        f32x4 z = {};
        z = MFMA(kf0, qa[qg][0], z);
        sT[qg][kg] = MFMA(kf1, qa[qg][1], z);
      }
    }
    __builtin_amdgcn_s_setprio(0);

    // ---- per-row max: register tree + 2 shfl ----
    float rm[2];
#pragma unroll
    for (int qg = 0; qg < 2; qg++){
      float m01 = fmaxf(fmaxf(sT[qg][0][0], sT[qg][0][1]), fmaxf(sT[qg][0][2], sT[qg][0][3]));
      float m23 = fmaxf(fmaxf(sT[qg][1][0], sT[qg][1][1]), fmaxf(sT[qg][1][2], sT[qg][1][3]));
      float m45 = fmaxf(fmaxf(sT[qg][2][0], sT[qg][2][1]), fmaxf(sT[qg][2][2], sT[qg][2][3]));
      float m67 = fmaxf(fmaxf(sT[qg][3][0], sT[qg][3][1]), fmaxf(sT[qg][3][2], sT[qg][3][3]));
      float v = fmaxf(fmaxf(m01, m23), fmaxf(m45, m67));
      v = fmaxf(v, __shfl_xor(v, 16));
      v = fmaxf(v, __shfl_xor(v, 32));
      rm[qg] = v;
    }

    // ---- defer-rescale: only pay al-mult when any row's max grew ----
    if (__any((rm[0] > mrunL[0]) | (rm[1] > mrunL[1]))){
#pragma unroll
      for (int qg = 0; qg < 2; qg++){
        float mo = mrunL[qg];
        float mn = fmaxf(mo, rm[qg]);
        float al = __builtin_exp2f(mo - mn);
        mrunL[qg] = mn;
        lsumL[qg] *= al;
#pragma unroll
        for (int dt = 0; dt < 4; dt++)
#pragma unroll
          for (int r = 0; r < 4; r++) acc[qg][dt][r] *= al;
      }
    }

    // ---- P = exp2(S - m), pack via cvt_pk, store to per-wave LDS ----
#pragma unroll
    for (int qg = 0; qg < 2; qg++){
      float mn = mrunL[qg];
      float ps = 0.f;
#pragma unroll
      for (int kg = 0; kg < 4; kg++){
        float p0 = __builtin_exp2f(sT[qg][kg][0] - mn);
        float p1 = __builtin_exp2f(sT[qg][kg][1] - mn);
        float p2 = __builtin_exp2f(sT[qg][kg][2] - mn);
        float p3 = __builtin_exp2f(sT[qg][kg][3] - mn);
        ps += (p0 + p1) + (p2 + p3);
        u32x2 pk; pk[0] = cvtpk(p0, p1); pk[1] = cvtpk(p2, p3);
        *(u32x2*)&pp[(qg * 16 + li) * 68 + kg * 16 + g * 4] = pk;
      }
      lsumL[qg] += ps;
    }

    // ---- O^T += V^T P^T : acc lane li = q-row li ----
    bf16x8 pf[2][2];
#pragma unroll
    for (int qg = 0; qg < 2; qg++){
      pf[qg][0] = *(const bf16x8*)&pp[(qg * 16 + li) * 68 + g * 8];
      pf[qg][1] = *(const bf16x8*)&pp[(qg * 16 + li) * 68 + 32 + g * 8];
    }
    __builtin_amdgcn_s_setprio(1);
#pragma unroll
    for (int dt = 0; dt < 4; dt++){
      bf16x8 vf0 = *(const bf16x8*)&smV[(dt * 16 + li) * 72 + g * 8];
      bf16x8 vf1 = *(const bf16x8*)&smV[(dt * 16 + li) * 72 + 32 + g * 8];
#pragma unroll
      for (int qg = 0; qg < 2; qg++){
        acc[qg][dt] = MFMA(vf0, pf[qg][0], acc[qg][dt]);
        acc[qg][dt] = MFMA(vf1, pf[qg][1], acc[qg][dt]);
      }
    }
    __builtin_amdgcn_s_setprio(0);
  }

  // ---- epilogue: 2-shfl sum reduce, lane-local normalize, u16x4 stores ----
#pragma unroll
  for (int qg = 0; qg < 2; qg++){
    float ls = lsumL[qg];
    ls += __shfl_xor(ls, 16);
    ls += __shfl_xor(ls, 32);
    float inv = 1.0f / ls;
    int qi = qb * 64 + w * 32 + qg * 16 + li;
    u16* dst; size_t basei;
    if (qi < L0){ dst = out0; basei = ((size_t)(b * L0 + qi)) * 1024 + h * 64; }
    else        { dst = out1; basei = ((size_t)(b * L1 + (qi - L0))) * 1024 + h * 64; }
#pragma unroll
    for (int dt = 0; dt < 4; dt++){
      u16x4 o;
#pragma unroll
      for (int r = 0; r < 4; r++) o[r] = f2bf(acc[qg][dt][r] * inv);
      *(u16x4*)&dst[basei + dt * 16 + g * 4] = o;
    }
  }
}

// ---------------- launch ----------------
extern "C" void kernel_launch(void* const* d_in, const int* in_sizes, int n_in,
                              void* d_out, int out_size, void* d_ws, size_t ws_size,
                              hipStream_t stream){
  (void)in_sizes; (void)n_in; (void)out_size; (void)ws_size;
  const float* x[3]    = {(const float*)d_in[0],  (const float*)d_in[7],  (const float*)d_in[14]};
  const float* Wqkv[3] = {(const float*)d_in[1],  (const float*)d_in[8],  (const float*)d_in[15]};
  const float* bqkv[3] = {(const float*)d_in[2],  (const float*)d_in[9],  (const float*)d_in[16]};
  const float* gq[3]   = {(const float*)d_in[3],  (const float*)d_in[10], (const float*)d_in[17]};
  const float* gk[3]   = {(const float*)d_in[4],  (const float*)d_in[11], (const float*)d_in[18]};
  const float* Wout[3] = {(const float*)d_in[5],  (const float*)d_in[12], (const float*)d_in[19]};
  const float* bout[3] = {(const float*)d_in[6],  (const float*)d_in[13], (const float*)d_in[20]};
  float* outp = (float*)d_out;

  const int Ms[3] = {4096, 2048, 1024};   // B*L per modality

  u16* base = (u16*)d_ws;
  size_t off = 0;
  auto nxt = [&](size_t e){ u16* r = base + off; off += e; return r; };
  u16* xbf[3];  for (int m = 0; m < 3; m++) xbf[m]  = nxt((size_t)Ms[m] * 1024);   // contiguous!
  u16* WqT[3];  for (int m = 0; m < 3; m++) WqT[m]  = nxt((size_t)3072 * 1024);
  u16* WoT[3];  for (int m = 0; m < 3; m++) WoT[m]  = nxt((size_t)1024 * 1024);
  u16* qkvb[3]; for (int m = 0; m < 3; m++) qkvb[m] = nxt((size_t)Ms[m] * 3072);
  u16* qA = nxt((size_t)2 * 16 * 2048 * 64);
  u16* qB = nxt((size_t)2 * 16 * 1536 * 64);
  u16* kB = nxt((size_t)2 * 16 * 3584 * 64);
  // aliases (disjoint lifetimes, stream-ordered):
  u16* vT = WqT[0];                        // vT reuses WqT block: WqT dead after QKV GEMMs
  u16* hb[3]; for (int m = 0; m < 3; m++) hb[m] = xbf[m];  // xbf dead after QKV GEMMs

  // 1) conversions: 2 dispatches
  cvt3<<<7168, 256, 0, stream>>>(x[0], x[1], x[2], xbf[0]);
  tcvt6<<<3072, 256, 0, stream>>>(Wqkv[0], Wqkv[1], Wqkv[2], Wout[0], Wout[1], Wout[2],
                                  WqT[0], WqT[1], WqT[2], WoT[0], WoT[1], WoT[2]);
  // 2) qkv projections - ONE merged dispatch (grid 24 x 56)
  gemm3<0><<<dim3(3072 / 128, 56), 256, 0, stream>>>(
      xbf[0], xbf[1], xbf[2], WqT[0], WqT[1], WqT[2],
      bqkv[0], bqkv[1], bqkv[2], qkvb[0], qkvb[1], qkvb[2],
      3072, 1024, 32, 16);
  // 3) RMS + scatter q/k (1 dispatch) ; transpose v (1 dispatch)
  rms3<<<7168, 256, 0, stream>>>(qkvb[0], qkvb[1], qkvb[2],
                                 gq[0], gk[0], gq[1], gk[1], gq[2], gk[2],
                                 qA, qB, kB);
  vtrans3<<<dim3(56, 16, 2), 256, 0, stream>>>(qkvb[0], qkvb[1], qkvb[2], vT);
  // 4) both attentions, single launch: 768 joint-attn blocks + 1024 self-attn blocks
  attn<<<1792, 128, 0, stream>>>(qA, qB, kB, vT, hb[0], hb[1], hb[2]);
  // 5) output projections - ONE merged dispatch (grid 8 x 56)
  float* outs[3] = {outp, outp + (size_t)4096 * 1024, outp + (size_t)6144 * 1024};
  gemm3<1><<<dim3(1024 / 128, 56), 256, 0, stream>>>(
      hb[0], hb[1], hb[2], WoT[0], WoT[1], WoT[2],
      bout[0], bout[1], bout[2], outs[0], outs[1], outs[2],
      1024, 1024, 32, 16);
}